// Round 1
// baseline (414.353 us; speedup 1.0000x reference)
//
#include <hip/hip_runtime.h>
#include <stdint.h>

#define NN 50000
#define NE 800000
#define POOL_BLOCKS 2048
#define AGG_THREADS 512

static __device__ __forceinline__ float bf2f(unsigned short u) {
    union { unsigned int i; float f; } v; v.i = ((unsigned int)u) << 16; return v.f;
}
static __device__ __forceinline__ unsigned short f2bf(float f) {
    union { float f; unsigned int i; } v; v.f = f;
    unsigned int x = v.i;
    x += 0x7fffu + ((x >> 16) & 1u);
    return (unsigned short)(x >> 16);
}

// h layout: h[node][c][q] bf16, q=0..3 = {sum,mean,max,std} part, c=channel 0..63
// thread j computes (c = j>>2, q = j&3)  ->  W_pool row r = q*64 + c
__global__ __launch_bounds__(256) void pool_kernel(
    const float* __restrict__ feat, const float* __restrict__ Wp,
    const float* __restrict__ bp, unsigned short* __restrict__ h)
{
    const int j = threadIdx.x;
    const int r = ((j & 3) << 6) + (j >> 2);
    float4 wv[16];
    const float4* Wp4 = (const float4*)(Wp + (size_t)r * 64);
    #pragma unroll
    for (int t = 0; t < 16; ++t) wv[t] = Wp4[t];
    const float bias = bp[r];
    const float4* f4 = (const float4*)feat;
    for (int g = blockIdx.x; g < NN / 4; g += gridDim.x) {
        const int n0 = g * 4;
        float acc[4];
        #pragma unroll
        for (int nb = 0; nb < 4; ++nb) acc[nb] = bias;
        #pragma unroll
        for (int t = 0; t < 16; ++t) {
            float4 w = wv[t];
            #pragma unroll
            for (int nb = 0; nb < 4; ++nb) {
                float4 x = f4[(size_t)(n0 + nb) * 16 + t];
                acc[nb] = fmaf(w.x, x.x, fmaf(w.y, x.y, fmaf(w.z, x.z, fmaf(w.w, x.w, acc[nb]))));
            }
        }
        #pragma unroll
        for (int nb = 0; nb < 4; ++nb)
            h[(size_t)(n0 + nb) * 256 + j] = f2bf(acc[nb]);
    }
}

__global__ __launch_bounds__(256) void count_kernel(const int* __restrict__ dst,
                                                    int* __restrict__ deg)
{
    int e = blockIdx.x * 256 + threadIdx.x;
    if (e < NE) atomicAdd(&deg[dst[e]], 1);
}

__global__ __launch_bounds__(256) void scan1(const int* __restrict__ deg, int* __restrict__ bsum)
{
    __shared__ int s[256];
    int t = threadIdx.x;
    int i = blockIdx.x * 256 + t;
    s[t] = (i < NN) ? deg[i] : 0;
    __syncthreads();
    for (int off = 128; off > 0; off >>= 1) {
        if (t < off) s[t] += s[t + off];
        __syncthreads();
    }
    if (t == 0) bsum[blockIdx.x] = s[0];
}

__global__ __launch_bounds__(256) void scan2(int* __restrict__ bsum, int nb)
{
    __shared__ int s[256];
    int t = threadIdx.x;
    int v = (t < nb) ? bsum[t] : 0;
    s[t] = v;
    __syncthreads();
    for (int off = 1; off < 256; off <<= 1) {
        int add = (t >= off) ? s[t - off] : 0;
        __syncthreads();
        s[t] += add;
        __syncthreads();
    }
    if (t < nb) bsum[t] = s[t] - v;   // exclusive
}

__global__ __launch_bounds__(256) void scan3(const int* __restrict__ deg,
                                             const int* __restrict__ bsum,
                                             int* __restrict__ offs)
{
    __shared__ int s[256];
    int t = threadIdx.x;
    int i = blockIdx.x * 256 + t;
    int v = (i < NN) ? deg[i] : 0;
    s[t] = v;
    __syncthreads();
    for (int off = 1; off < 256; off <<= 1) {
        int add = (t >= off) ? s[t - off] : 0;
        __syncthreads();
        s[t] += add;
        __syncthreads();
    }
    if (i < NN) offs[i] = bsum[blockIdx.x] + s[t] - v;
    if (blockIdx.x == 0 && t == 0) offs[NN] = NE;
}

__global__ __launch_bounds__(256) void scatter_kernel(
    const int* __restrict__ src, const int* __restrict__ dst,
    const float* __restrict__ w, const int* __restrict__ offs,
    int* __restrict__ cursor, int2* __restrict__ csr)
{
    int e = blockIdx.x * 256 + threadIdx.x;
    if (e < NE) {
        int d = dst[e];
        int p = offs[d] + atomicAdd(&cursor[d], 1);
        csr[p] = make_int2(src[e], __float_as_int(w[e]));
    }
}

// fused aggregate + epilogue: 8 waves/block, each wave handles 4 nodes per pass
__global__ __launch_bounds__(AGG_THREADS) void agg_kernel(
    const unsigned short* __restrict__ h,   // [N][64][4] bf16
    const float* __restrict__ feat,
    const int* __restrict__ offs,
    const int2* __restrict__ csr,
    const float* __restrict__ Wn,           // [64][320]
    const float* __restrict__ bn,           // [64]
    float* __restrict__ out)                // [N][64]
{
    __shared__ float wnT[320 * 65];                      // wnT[k*65+o] = Wn[o][k]
    __shared__ __align__(16) float xs[8][4][320];        // per-wave, per-node concat vec

    const int tid = threadIdx.x;
    for (int e = tid; e < 64 * 320; e += AGG_THREADS) {
        int o = e / 320, k = e - o * 320;
        wnT[k * 65 + o] = Wn[e];
    }
    __syncthreads();

    const int wave = tid >> 6;
    const int lane = tid & 63;
    const float bias = bn[lane];
    const ushort4* h4 = (const ushort4*)h;               // [N][64] of ushort4

    const int groups = NN / 4;                           // 12500
    for (int g = blockIdx.x * 8 + wave; g < groups; g += gridDim.x * 8) {
        const int n0 = g * 4;
        float s0[4], s1[4], s3[4], s2[4], vmx[4];
        #pragma unroll
        for (int nb = 0; nb < 4; ++nb) { s0[nb]=0.f; s1[nb]=0.f; s3[nb]=0.f; s2[nb]=0.f; vmx[nb]=-INFINITY; }

        #pragma unroll
        for (int nb = 0; nb < 4; ++nb) {
            const int n = n0 + nb;
            const int rs = offs[n], re = offs[n + 1];
            for (int base = rs; base < re; base += 64) {
                const int cnt = min(64, re - base);
                int sl = 0; float wl = 0.f;
                if (lane < cnt) {
                    int2 ew = csr[base + lane];
                    sl = ew.x; wl = __int_as_float(ew.y);
                }
                for (int jj = 0; jj < cnt; ++jj) {
                    int   sj = __shfl(sl, jj);
                    float wj = __shfl(wl, jj);
                    ushort4 hv = h4[(size_t)sj * 64 + lane];
                    float a  = bf2f(hv.x);
                    float bm = bf2f(hv.y);
                    float mx = bf2f(hv.z);
                    float sd = bf2f(hv.w);
                    s0[nb] += wj * a;
                    s1[nb] += wj * bm;
                    vmx[nb] = fmaxf(vmx[nb], wj * mx);
                    s3[nb] += wj * sd;
                    s2[nb] += wj * sd * sd;
                }
            }
        }

        // finalize stats and stage x = [feat | agg_sum | agg_mean | agg_max | agg_std]
        #pragma unroll
        for (int nb = 0; nb < 4; ++nb) {
            const int n = n0 + nb;
            const int dg = offs[n + 1] - offs[n];
            float fsum, fmean, fmx, fstd;
            if (dg == 0) { fsum = fmean = fmx = fstd = 0.f; }
            else {
                const float inv = 1.0f / (float)dg;
                fsum  = s0[nb];
                fmean = s1[nb] * inv;
                fmx   = vmx[nb];
                const float m1 = s3[nb] * inv;
                const float m2 = s2[nb] * inv;
                fstd  = m2 - m1 * m1;
            }
            float* xp = xs[wave][nb];
            xp[lane]        = feat[(size_t)n * 64 + lane];
            xp[64  + lane]  = fsum;
            xp[128 + lane]  = fmean;
            xp[192 + lane]  = fmx;
            xp[256 + lane]  = fstd;
        }
        __builtin_amdgcn_wave_barrier();   // same-wave LDS write->read ordering fence

        // epilogue: out[n][o] = sum_k x[k] * Wn[o][k] + bn[o], o = lane, 4 nodes batched
        float a0 = bias, a1 = bias, a2 = bias, a3 = bias;
        const float4* x0 = (const float4*)xs[wave][0];
        const float4* x1 = (const float4*)xs[wave][1];
        const float4* x2 = (const float4*)xs[wave][2];
        const float4* x3 = (const float4*)xs[wave][3];
        #pragma unroll 4
        for (int kk = 0; kk < 80; ++kk) {
            float4 q0 = x0[kk], q1 = x1[kk], q2 = x2[kk], q3 = x3[kk];
            float w0 = wnT[(kk * 4 + 0) * 65 + lane];
            float w1 = wnT[(kk * 4 + 1) * 65 + lane];
            float w2 = wnT[(kk * 4 + 2) * 65 + lane];
            float w3 = wnT[(kk * 4 + 3) * 65 + lane];
            a0 = fmaf(q0.x, w0, fmaf(q0.y, w1, fmaf(q0.z, w2, fmaf(q0.w, w3, a0))));
            a1 = fmaf(q1.x, w0, fmaf(q1.y, w1, fmaf(q1.z, w2, fmaf(q1.w, w3, a1))));
            a2 = fmaf(q2.x, w0, fmaf(q2.y, w1, fmaf(q2.z, w2, fmaf(q2.w, w3, a2))));
            a3 = fmaf(q3.x, w0, fmaf(q3.y, w1, fmaf(q3.z, w2, fmaf(q3.w, w3, a3))));
        }
        out[(size_t)(n0 + 0) * 64 + lane] = a0;
        out[(size_t)(n0 + 1) * 64 + lane] = a1;
        out[(size_t)(n0 + 2) * 64 + lane] = a2;
        out[(size_t)(n0 + 3) * 64 + lane] = a3;
    }
}

extern "C" void kernel_launch(void* const* d_in, const int* in_sizes, int n_in,
                              void* d_out, int out_size, void* d_ws, size_t ws_size,
                              hipStream_t stream)
{
    const float* feat   = (const float*)d_in[0];
    const float* weight = (const float*)d_in[1];
    const int*   src    = (const int*)d_in[2];
    const int*   dst    = (const int*)d_in[3];
    const float* Wp     = (const float*)d_in[4];
    const float* bp     = (const float*)d_in[5];
    const float* Wn     = (const float*)d_in[6];
    const float* bn     = (const float*)d_in[7];
    float* out = (float*)d_out;

    char* ws = (char*)d_ws;
    size_t cur = 0;
    auto alloc = [&](size_t bytes) -> void* {
        cur = (cur + 255) & ~(size_t)255;
        void* p = ws + cur;
        cur += bytes;
        return p;
    };

    unsigned short* h  = (unsigned short*)alloc((size_t)NN * 256 * 2);
    int* degcur        = (int*)alloc((size_t)2 * NN * 4);   // deg | cursor, one memset
    int* deg    = degcur;
    int* cursor = degcur + NN;
    int* offs   = (int*)alloc((size_t)(NN + 1) * 4);
    int* bsum   = (int*)alloc(1024);
    int2* csr   = (int2*)alloc((size_t)NE * 8);
    (void)ws_size; (void)in_sizes; (void)n_in; (void)out_size;

    hipMemsetAsync(degcur, 0, (size_t)2 * NN * 4, stream);

    pool_kernel<<<POOL_BLOCKS, 256, 0, stream>>>(feat, Wp, bp, h);
    count_kernel<<<(NE + 255) / 256, 256, 0, stream>>>(dst, deg);
    scan1<<<(NN + 255) / 256, 256, 0, stream>>>(deg, bsum);
    scan2<<<1, 256, 0, stream>>>(bsum, (NN + 255) / 256);
    scan3<<<(NN + 255) / 256, 256, 0, stream>>>(deg, bsum, offs);
    scatter_kernel<<<(NE + 255) / 256, 256, 0, stream>>>(src, dst, weight, offs, cursor, csr);
    agg_kernel<<<(NN / 4 + 7) / 8, AGG_THREADS, 0, stream>>>(h, feat, offs, csr, Wn, bn, out);
}

// Round 2
// 369.042 us; speedup vs baseline: 1.1228x; 1.1228x over previous
//
#include <hip/hip_runtime.h>
#include <stdint.h>

#define NN 50000
#define NE 800000
#define POOL_BLOCKS 2048
#define NGROUP 12500          // NN/4
#define EPI_THREADS 1024

static __device__ __forceinline__ float bf2f(unsigned short u) {
    union { unsigned int i; float f; } v; v.i = ((unsigned int)u) << 16; return v.f;
}
static __device__ __forceinline__ unsigned short f2bf(float f) {
    union { float f; unsigned int i; } v; v.f = f;
    unsigned int x = v.i;
    x += 0x7fffu + ((x >> 16) & 1u);
    return (unsigned short)(x >> 16);
}

// h layout: h[node][c][q] bf16, q=0..3 = {sum,mean,max,std} part, c=channel 0..63
// thread j computes (c = j>>2, q = j&3)  ->  W_pool row r = q*64 + c
__global__ __launch_bounds__(256) void pool_kernel(
    const float* __restrict__ feat, const float* __restrict__ Wp,
    const float* __restrict__ bp, unsigned short* __restrict__ h)
{
    const int j = threadIdx.x;
    const int r = ((j & 3) << 6) + (j >> 2);
    float4 wv[16];
    const float4* Wp4 = (const float4*)(Wp + (size_t)r * 64);
    #pragma unroll
    for (int t = 0; t < 16; ++t) wv[t] = Wp4[t];
    const float bias = bp[r];
    const float4* f4 = (const float4*)feat;
    for (int g = blockIdx.x; g < NN / 4; g += gridDim.x) {
        const int n0 = g * 4;
        float acc[4];
        #pragma unroll
        for (int nb = 0; nb < 4; ++nb) acc[nb] = bias;
        #pragma unroll
        for (int t = 0; t < 16; ++t) {
            float4 w = wv[t];
            #pragma unroll
            for (int nb = 0; nb < 4; ++nb) {
                float4 x = f4[(size_t)(n0 + nb) * 16 + t];
                acc[nb] = fmaf(w.x, x.x, fmaf(w.y, x.y, fmaf(w.z, x.z, fmaf(w.w, x.w, acc[nb]))));
            }
        }
        #pragma unroll
        for (int nb = 0; nb < 4; ++nb)
            h[(size_t)(n0 + nb) * 256 + j] = f2bf(acc[nb]);
    }
}

__global__ __launch_bounds__(256) void count_kernel(const int* __restrict__ dst,
                                                    int* __restrict__ deg)
{
    int e = blockIdx.x * 256 + threadIdx.x;
    if (e < NE) atomicAdd(&deg[dst[e]], 1);
}

__global__ __launch_bounds__(256) void scan1(const int* __restrict__ deg, int* __restrict__ bsum)
{
    __shared__ int s[256];
    int t = threadIdx.x;
    int i = blockIdx.x * 256 + t;
    s[t] = (i < NN) ? deg[i] : 0;
    __syncthreads();
    for (int off = 128; off > 0; off >>= 1) {
        if (t < off) s[t] += s[t + off];
        __syncthreads();
    }
    if (t == 0) bsum[blockIdx.x] = s[0];
}

__global__ __launch_bounds__(256) void scan2(int* __restrict__ bsum, int nb)
{
    __shared__ int s[256];
    int t = threadIdx.x;
    int v = (t < nb) ? bsum[t] : 0;
    s[t] = v;
    __syncthreads();
    for (int off = 1; off < 256; off <<= 1) {
        int add = (t >= off) ? s[t - off] : 0;
        __syncthreads();
        s[t] += add;
        __syncthreads();
    }
    if (t < nb) bsum[t] = s[t] - v;   // exclusive
}

__global__ __launch_bounds__(256) void scan3(const int* __restrict__ deg,
                                             const int* __restrict__ bsum,
                                             int* __restrict__ offs)
{
    __shared__ int s[256];
    int t = threadIdx.x;
    int i = blockIdx.x * 256 + t;
    int v = (i < NN) ? deg[i] : 0;
    s[t] = v;
    __syncthreads();
    for (int off = 1; off < 256; off <<= 1) {
        int add = (t >= off) ? s[t - off] : 0;
        __syncthreads();
        s[t] += add;
        __syncthreads();
    }
    if (i < NN) offs[i] = bsum[blockIdx.x] + s[t] - v;
    if (blockIdx.x == 0 && t == 0) offs[NN] = NE;
}

__global__ __launch_bounds__(256) void scatter_kernel(
    const int* __restrict__ src, const int* __restrict__ dst,
    const float* __restrict__ w, const int* __restrict__ offs,
    int* __restrict__ cursor, int2* __restrict__ csr)
{
    int e = blockIdx.x * 256 + threadIdx.x;
    if (e < NE) {
        int d = dst[e];
        int p = offs[d] + atomicAdd(&cursor[d], 1);
        csr[p] = make_int2(src[e], __float_as_int(w[e]));
    }
}

// gather: no LDS, 4 waves/block, each wave owns 4 nodes. 8-deep load pipeline.
// writes finalized stats x2[n][256] = [sum | mean | max | std] f32
__global__ __launch_bounds__(256) void gather_kernel(
    const unsigned short* __restrict__ h,   // [N][64][4] bf16
    const int* __restrict__ offs,
    const int2* __restrict__ csr,
    float* __restrict__ x2)                 // [N][256]
{
    const int wave = threadIdx.x >> 6;
    const int lane = threadIdx.x & 63;
    const int g = blockIdx.x * 4 + wave;
    if (g >= NGROUP) return;
    const int n0 = g * 4;
    const ushort4* h4 = (const ushort4*)h;   // [N][64] of ushort4

    float s0[4], s1[4], s3[4], s2[4], vmx[4];
    #pragma unroll
    for (int nb = 0; nb < 4; ++nb) { s0[nb]=0.f; s1[nb]=0.f; s3[nb]=0.f; s2[nb]=0.f; vmx[nb]=-INFINITY; }

    #pragma unroll
    for (int nb = 0; nb < 4; ++nb) {
        const int n = n0 + nb;
        const int rs = offs[n], re = offs[n + 1];
        for (int base = rs; base < re; base += 64) {
            const int cnt = min(64, re - base);
            int sl = 0; int wli = 0;
            if (lane < cnt) {
                int2 ew = csr[base + lane];
                sl = ew.x; wli = ew.y;
            }
            int jj = 0;
            for (; jj + 8 <= cnt; jj += 8) {
                ushort4 hv[8];
                #pragma unroll
                for (int u = 0; u < 8; ++u) {
                    int sj = __builtin_amdgcn_readlane(sl, jj + u);
                    hv[u] = h4[(size_t)sj * 64 + lane];
                }
                #pragma unroll
                for (int u = 0; u < 8; ++u) {
                    float wj = __int_as_float(__builtin_amdgcn_readlane(wli, jj + u));
                    float a  = bf2f(hv[u].x);
                    float bm = bf2f(hv[u].y);
                    float mx = bf2f(hv[u].z);
                    float sd = bf2f(hv[u].w);
                    s0[nb] = fmaf(wj, a, s0[nb]);
                    s1[nb] = fmaf(wj, bm, s1[nb]);
                    vmx[nb] = fmaxf(vmx[nb], wj * mx);
                    s3[nb] = fmaf(wj, sd, s3[nb]);
                    s2[nb] = fmaf(wj * sd, sd, s2[nb]);
                }
            }
            for (; jj < cnt; ++jj) {
                int   sj = __builtin_amdgcn_readlane(sl, jj);
                float wj = __int_as_float(__builtin_amdgcn_readlane(wli, jj));
                ushort4 hv = h4[(size_t)sj * 64 + lane];
                float a  = bf2f(hv.x);
                float bm = bf2f(hv.y);
                float mx = bf2f(hv.z);
                float sd = bf2f(hv.w);
                s0[nb] = fmaf(wj, a, s0[nb]);
                s1[nb] = fmaf(wj, bm, s1[nb]);
                vmx[nb] = fmaxf(vmx[nb], wj * mx);
                s3[nb] = fmaf(wj, sd, s3[nb]);
                s2[nb] = fmaf(wj * sd, sd, s2[nb]);
            }
        }
    }

    #pragma unroll
    for (int nb = 0; nb < 4; ++nb) {
        const int n = n0 + nb;
        const int dg = offs[n + 1] - offs[n];
        float fsum, fmean, fmx, fstd;
        if (dg == 0) { fsum = fmean = fmx = fstd = 0.f; }
        else {
            const float inv = 1.0f / (float)dg;
            fsum  = s0[nb];
            fmean = s1[nb] * inv;
            fmx   = vmx[nb];
            const float m1 = s3[nb] * inv;
            const float m2 = s2[nb] * inv;
            fstd  = m2 - m1 * m1;
        }
        float* xp = x2 + (size_t)n * 256;
        xp[lane]       = fsum;
        xp[64  + lane] = fmean;
        xp[128 + lane] = fmx;
        xp[192 + lane] = fstd;
    }
}

// epilogue: out[n][o] = [feat(n) | x2(n)] . Wn[o][:] + bn[o]
// 16 waves/block, wave owns 4 nodes, lane = o. x rows read as wave-uniform float4.
__global__ __launch_bounds__(EPI_THREADS) void epi_kernel(
    const float* __restrict__ feat,
    const float* __restrict__ x2,
    const float* __restrict__ Wn,           // [64][320]
    const float* __restrict__ bn,
    float* __restrict__ out)
{
    __shared__ float wnT[320 * 65];          // wnT[k*65+o] = Wn[o][k]
    const int tid = threadIdx.x;
    for (int e = tid; e < 64 * 320; e += EPI_THREADS) {
        int o = e / 320, k = e - o * 320;
        wnT[k * 65 + o] = Wn[e];
    }
    __syncthreads();

    const int wave = tid >> 6;
    const int lane = tid & 63;
    const int g = blockIdx.x * 16 + wave;
    if (g >= NGROUP) return;
    const int n0 = g * 4;
    const float bias = bn[lane];
    float a0 = bias, a1 = bias, a2 = bias, a3 = bias;

    const float4* f4 = (const float4*)feat;  // [N][16]
    const float4* x4 = (const float4*)x2;    // [N][64]

    #pragma unroll 4
    for (int kk = 0; kk < 16; ++kk) {
        float4 q0 = f4[(size_t)(n0 + 0) * 16 + kk];
        float4 q1 = f4[(size_t)(n0 + 1) * 16 + kk];
        float4 q2 = f4[(size_t)(n0 + 2) * 16 + kk];
        float4 q3 = f4[(size_t)(n0 + 3) * 16 + kk];
        float w0 = wnT[(kk * 4 + 0) * 65 + lane];
        float w1 = wnT[(kk * 4 + 1) * 65 + lane];
        float w2 = wnT[(kk * 4 + 2) * 65 + lane];
        float w3 = wnT[(kk * 4 + 3) * 65 + lane];
        a0 = fmaf(q0.x, w0, fmaf(q0.y, w1, fmaf(q0.z, w2, fmaf(q0.w, w3, a0))));
        a1 = fmaf(q1.x, w0, fmaf(q1.y, w1, fmaf(q1.z, w2, fmaf(q1.w, w3, a1))));
        a2 = fmaf(q2.x, w0, fmaf(q2.y, w1, fmaf(q2.z, w2, fmaf(q2.w, w3, a2))));
        a3 = fmaf(q3.x, w0, fmaf(q3.y, w1, fmaf(q3.z, w2, fmaf(q3.w, w3, a3))));
    }
    #pragma unroll 4
    for (int kk = 0; kk < 64; ++kk) {
        float4 q0 = x4[(size_t)(n0 + 0) * 64 + kk];
        float4 q1 = x4[(size_t)(n0 + 1) * 64 + kk];
        float4 q2 = x4[(size_t)(n0 + 2) * 64 + kk];
        float4 q3 = x4[(size_t)(n0 + 3) * 64 + kk];
        const int kb = 64 + kk * 4;
        float w0 = wnT[(kb + 0) * 65 + lane];
        float w1 = wnT[(kb + 1) * 65 + lane];
        float w2 = wnT[(kb + 2) * 65 + lane];
        float w3 = wnT[(kb + 3) * 65 + lane];
        a0 = fmaf(q0.x, w0, fmaf(q0.y, w1, fmaf(q0.z, w2, fmaf(q0.w, w3, a0))));
        a1 = fmaf(q1.x, w0, fmaf(q1.y, w1, fmaf(q1.z, w2, fmaf(q1.w, w3, a1))));
        a2 = fmaf(q2.x, w0, fmaf(q2.y, w1, fmaf(q2.z, w2, fmaf(q2.w, w3, a2))));
        a3 = fmaf(q3.x, w0, fmaf(q3.y, w1, fmaf(q3.z, w2, fmaf(q3.w, w3, a3))));
    }

    out[(size_t)(n0 + 0) * 64 + lane] = a0;
    out[(size_t)(n0 + 1) * 64 + lane] = a1;
    out[(size_t)(n0 + 2) * 64 + lane] = a2;
    out[(size_t)(n0 + 3) * 64 + lane] = a3;
}

extern "C" void kernel_launch(void* const* d_in, const int* in_sizes, int n_in,
                              void* d_out, int out_size, void* d_ws, size_t ws_size,
                              hipStream_t stream)
{
    const float* feat   = (const float*)d_in[0];
    const float* weight = (const float*)d_in[1];
    const int*   src    = (const int*)d_in[2];
    const int*   dst    = (const int*)d_in[3];
    const float* Wp     = (const float*)d_in[4];
    const float* bp     = (const float*)d_in[5];
    const float* Wn     = (const float*)d_in[6];
    const float* bn     = (const float*)d_in[7];
    float* out = (float*)d_out;

    char* ws = (char*)d_ws;
    size_t cur = 0;
    auto alloc = [&](size_t bytes) -> void* {
        cur = (cur + 255) & ~(size_t)255;
        void* p = ws + cur;
        cur += bytes;
        return p;
    };

    unsigned short* h  = (unsigned short*)alloc((size_t)NN * 256 * 2);
    int* degcur        = (int*)alloc((size_t)2 * NN * 4);   // deg | cursor, one memset
    int* deg    = degcur;
    int* cursor = degcur + NN;
    int* offs   = (int*)alloc((size_t)(NN + 1) * 4);
    int* bsum   = (int*)alloc(1024);
    int2* csr   = (int2*)alloc((size_t)NE * 8);
    float* x2   = (float*)alloc((size_t)NN * 256 * 4);
    (void)ws_size; (void)in_sizes; (void)n_in; (void)out_size;

    hipMemsetAsync(degcur, 0, (size_t)2 * NN * 4, stream);

    pool_kernel<<<POOL_BLOCKS, 256, 0, stream>>>(feat, Wp, bp, h);
    count_kernel<<<(NE + 255) / 256, 256, 0, stream>>>(dst, deg);
    scan1<<<(NN + 255) / 256, 256, 0, stream>>>(deg, bsum);
    scan2<<<1, 256, 0, stream>>>(bsum, (NN + 255) / 256);
    scan3<<<(NN + 255) / 256, 256, 0, stream>>>(deg, bsum, offs);
    scatter_kernel<<<(NE + 255) / 256, 256, 0, stream>>>(src, dst, weight, offs, cursor, csr);
    gather_kernel<<<(NGROUP + 3) / 4, 256, 0, stream>>>(h, offs, csr, x2);
    epi_kernel<<<(NGROUP + 15) / 16, EPI_THREADS, 0, stream>>>(feat, x2, Wn, bn, out);
}

// Round 3
// 245.098 us; speedup vs baseline: 1.6906x; 1.5057x over previous
//
#include <hip/hip_runtime.h>
#include <stdint.h>

#define NN 50000
#define NE 800000
#define POOL_BLOCKS 2048
#define NGROUP 12500          // NN/4
#define NTILE 3125            // NN/16 M-tiles for epi MFMA

typedef __attribute__((ext_vector_type(8))) short short8v;   // 8 bf16 (4 VGPRs)
typedef __attribute__((ext_vector_type(4))) float f32x4;

static __device__ __forceinline__ float bf2f(unsigned short u) {
    union { unsigned int i; float f; } v; v.i = ((unsigned int)u) << 16; return v.f;
}
static __device__ __forceinline__ unsigned short f2bf(float f) {
    union { float f; unsigned int i; } v; v.f = f;
    unsigned int x = v.i;
    x += 0x7fffu + ((x >> 16) & 1u);
    return (unsigned short)(x >> 16);
}
static __device__ __forceinline__ unsigned int pkbf(float lo, float hi) {
    return (unsigned int)f2bf(lo) | ((unsigned int)f2bf(hi) << 16);
}

// h layout: h[node][c][q] bf16, q=0..3 = {sum,mean,max,std} part, c=channel 0..63
// thread j computes (c = j>>2, q = j&3)  ->  W_pool row r = q*64 + c
__global__ __launch_bounds__(256) void pool_kernel(
    const float* __restrict__ feat, const float* __restrict__ Wp,
    const float* __restrict__ bp, unsigned short* __restrict__ h)
{
    const int j = threadIdx.x;
    const int r = ((j & 3) << 6) + (j >> 2);
    float4 wv[16];
    const float4* Wp4 = (const float4*)(Wp + (size_t)r * 64);
    #pragma unroll
    for (int t = 0; t < 16; ++t) wv[t] = Wp4[t];
    const float bias = bp[r];
    const float4* f4 = (const float4*)feat;
    for (int g = blockIdx.x; g < NN / 4; g += gridDim.x) {
        const int n0 = g * 4;
        float acc[4];
        #pragma unroll
        for (int nb = 0; nb < 4; ++nb) acc[nb] = bias;
        #pragma unroll
        for (int t = 0; t < 16; ++t) {
            float4 w = wv[t];
            #pragma unroll
            for (int nb = 0; nb < 4; ++nb) {
                float4 x = f4[(size_t)(n0 + nb) * 16 + t];
                acc[nb] = fmaf(w.x, x.x, fmaf(w.y, x.y, fmaf(w.z, x.z, fmaf(w.w, x.w, acc[nb]))));
            }
        }
        #pragma unroll
        for (int nb = 0; nb < 4; ++nb)
            h[(size_t)(n0 + nb) * 256 + j] = f2bf(acc[nb]);
    }
}

__global__ __launch_bounds__(256) void count_kernel(const int* __restrict__ dst,
                                                    int* __restrict__ deg)
{
    int e = blockIdx.x * 256 + threadIdx.x;
    if (e < NE) atomicAdd(&deg[dst[e]], 1);
}

__global__ __launch_bounds__(256) void scan1(const int* __restrict__ deg, int* __restrict__ bsum)
{
    __shared__ int s[256];
    int t = threadIdx.x;
    int i = blockIdx.x * 256 + t;
    s[t] = (i < NN) ? deg[i] : 0;
    __syncthreads();
    for (int off = 128; off > 0; off >>= 1) {
        if (t < off) s[t] += s[t + off];
        __syncthreads();
    }
    if (t == 0) bsum[blockIdx.x] = s[0];
}

__global__ __launch_bounds__(256) void scan2(int* __restrict__ bsum, int nb)
{
    __shared__ int s[256];
    int t = threadIdx.x;
    int v = (t < nb) ? bsum[t] : 0;
    s[t] = v;
    __syncthreads();
    for (int off = 1; off < 256; off <<= 1) {
        int add = (t >= off) ? s[t - off] : 0;
        __syncthreads();
        s[t] += add;
        __syncthreads();
    }
    if (t < nb) bsum[t] = s[t] - v;   // exclusive
}

__global__ __launch_bounds__(256) void scan3(const int* __restrict__ deg,
                                             const int* __restrict__ bsum,
                                             int* __restrict__ offs)
{
    __shared__ int s[256];
    int t = threadIdx.x;
    int i = blockIdx.x * 256 + t;
    int v = (i < NN) ? deg[i] : 0;
    s[t] = v;
    __syncthreads();
    for (int off = 1; off < 256; off <<= 1) {
        int add = (t >= off) ? s[t - off] : 0;
        __syncthreads();
        s[t] += add;
        __syncthreads();
    }
    if (i < NN) offs[i] = bsum[blockIdx.x] + s[t] - v;
    if (blockIdx.x == 0 && t == 0) offs[NN] = NE;
}

__global__ __launch_bounds__(256) void scatter_kernel(
    const int* __restrict__ src, const int* __restrict__ dst,
    const float* __restrict__ w, const int* __restrict__ offs,
    int* __restrict__ cursor, int2* __restrict__ csr)
{
    int e = blockIdx.x * 256 + threadIdx.x;
    if (e < NE) {
        int d = dst[e];
        int p = offs[d] + atomicAdd(&cursor[d], 1);
        csr[p] = make_int2(src[e], __float_as_int(w[e]));
    }
}

__global__ __launch_bounds__(256) void cvt_wn_kernel(const float* __restrict__ Wn,
                                                     unsigned short* __restrict__ wnb)
{
    int i = blockIdx.x * 256 + threadIdx.x;
    if (i < 64 * 320) wnb[i] = f2bf(Wn[i]);
}

// gather: no LDS, 4 waves/block, each wave owns 4 nodes. 8-deep load pipeline.
// writes finalized stats x2b[n][256] = [sum | mean | max | std] bf16
__global__ __launch_bounds__(256) void gather_kernel(
    const unsigned short* __restrict__ h,   // [N][64][4] bf16
    const int* __restrict__ offs,
    const int2* __restrict__ csr,
    unsigned short* __restrict__ x2b)       // [N][256] bf16
{
    const int wave = threadIdx.x >> 6;
    const int lane = threadIdx.x & 63;
    const int g = blockIdx.x * 4 + wave;
    if (g >= NGROUP) return;
    const int n0 = g * 4;
    const ushort4* h4 = (const ushort4*)h;   // [N][64] of ushort4

    float s0[4], s1[4], s3[4], s2[4], vmx[4];
    #pragma unroll
    for (int nb = 0; nb < 4; ++nb) { s0[nb]=0.f; s1[nb]=0.f; s3[nb]=0.f; s2[nb]=0.f; vmx[nb]=-INFINITY; }

    #pragma unroll
    for (int nb = 0; nb < 4; ++nb) {
        const int n = n0 + nb;
        const int rs = offs[n], re = offs[n + 1];
        for (int base = rs; base < re; base += 64) {
            const int cnt = min(64, re - base);
            int sl = 0; int wli = 0;
            if (lane < cnt) {
                int2 ew = csr[base + lane];
                sl = ew.x; wli = ew.y;
            }
            int jj = 0;
            for (; jj + 8 <= cnt; jj += 8) {
                ushort4 hv[8];
                #pragma unroll
                for (int u = 0; u < 8; ++u) {
                    int sj = __builtin_amdgcn_readlane(sl, jj + u);
                    hv[u] = h4[(size_t)sj * 64 + lane];
                }
                #pragma unroll
                for (int u = 0; u < 8; ++u) {
                    float wj = __int_as_float(__builtin_amdgcn_readlane(wli, jj + u));
                    float a  = bf2f(hv[u].x);
                    float bm = bf2f(hv[u].y);
                    float mx = bf2f(hv[u].z);
                    float sd = bf2f(hv[u].w);
                    s0[nb] = fmaf(wj, a, s0[nb]);
                    s1[nb] = fmaf(wj, bm, s1[nb]);
                    vmx[nb] = fmaxf(vmx[nb], wj * mx);
                    s3[nb] = fmaf(wj, sd, s3[nb]);
                    s2[nb] = fmaf(wj * sd, sd, s2[nb]);
                }
            }
            for (; jj < cnt; ++jj) {
                int   sj = __builtin_amdgcn_readlane(sl, jj);
                float wj = __int_as_float(__builtin_amdgcn_readlane(wli, jj));
                ushort4 hv = h4[(size_t)sj * 64 + lane];
                float a  = bf2f(hv.x);
                float bm = bf2f(hv.y);
                float mx = bf2f(hv.z);
                float sd = bf2f(hv.w);
                s0[nb] = fmaf(wj, a, s0[nb]);
                s1[nb] = fmaf(wj, bm, s1[nb]);
                vmx[nb] = fmaxf(vmx[nb], wj * mx);
                s3[nb] = fmaf(wj, sd, s3[nb]);
                s2[nb] = fmaf(wj * sd, sd, s2[nb]);
            }
        }
    }

    #pragma unroll
    for (int nb = 0; nb < 4; ++nb) {
        const int n = n0 + nb;
        const int dg = offs[n + 1] - offs[n];
        float fsum, fmean, fmx, fstd;
        if (dg == 0) { fsum = fmean = fmx = fstd = 0.f; }
        else {
            const float inv = 1.0f / (float)dg;
            fsum  = s0[nb];
            fmean = s1[nb] * inv;
            fmx   = vmx[nb];
            const float m1 = s3[nb] * inv;
            const float m2 = s2[nb] * inv;
            fstd  = m2 - m1 * m1;
        }
        unsigned short* xp = x2b + (size_t)n * 256;
        xp[lane]       = f2bf(fsum);
        xp[64  + lane] = f2bf(fmean);
        xp[128 + lane] = f2bf(fmx);
        xp[192 + lane] = f2bf(fstd);
    }
}

// MFMA epilogue: out[50000x64] = [feat | x2b] (50000x320) @ WnT(320x64) + bn
// 4 waves/block; wave owns one 16-row M-tile, all 64 output cols (4 acc tiles).
// A-frag: lane row = l&15, k = 8*(l>>4)+e. B-frag from row-major Wnb[n][k]
// (= B^T). D: row = (l>>4)*4+i, col = l&15   [m89-verified layout]
__global__ __launch_bounds__(256) void epi_mfma_kernel(
    const float* __restrict__ feat,
    const unsigned short* __restrict__ x2b,  // [N][256] bf16
    const unsigned short* __restrict__ wnb,  // [64][320] bf16
    const float* __restrict__ bn,
    float* __restrict__ out)
{
    const int wave = threadIdx.x >> 6;
    const int lane = threadIdx.x & 63;
    const int tile = blockIdx.x * 4 + wave;
    if (tile >= NTILE) return;
    const int m0  = tile * 16;
    const int row = m0 + (lane & 15);
    const int kq  = (lane >> 4) * 8;         // k sub-offset within a 32-step
    const int nr  = lane & 15;

    f32x4 acc[4];
    #pragma unroll
    for (int t = 0; t < 4; ++t) acc[t] = (f32x4){0.f, 0.f, 0.f, 0.f};

    const short8v* wn8 = (const short8v*)wnb;   // [64][40] of short8

    // k-steps 0..1: A from feat (f32 -> bf16 inline)
    #pragma unroll
    for (int s = 0; s < 2; ++s) {
        const float4* fp = (const float4*)(feat + (size_t)row * 64 + s * 32 + kq);
        float4 fa = fp[0], fb = fp[1];
        union { unsigned int u[4]; short8v v; } au;
        au.u[0] = pkbf(fa.x, fa.y); au.u[1] = pkbf(fa.z, fa.w);
        au.u[2] = pkbf(fb.x, fb.y); au.u[3] = pkbf(fb.z, fb.w);
        #pragma unroll
        for (int t = 0; t < 4; ++t) {
            short8v b = wn8[((t * 16 + nr) * 320 + s * 32 + kq) >> 3];
            acc[t] = __builtin_amdgcn_mfma_f32_16x16x32_bf16(au.v, b, acc[t], 0, 0, 0);
        }
    }
    // k-steps 2..9: A from x2b stats
    #pragma unroll
    for (int s = 2; s < 10; ++s) {
        short8v a = *(const short8v*)(x2b + (size_t)row * 256 + (s - 2) * 32 + kq);
        #pragma unroll
        for (int t = 0; t < 4; ++t) {
            short8v b = wn8[((t * 16 + nr) * 320 + s * 32 + kq) >> 3];
            acc[t] = __builtin_amdgcn_mfma_f32_16x16x32_bf16(a, b, acc[t], 0, 0, 0);
        }
    }

    const int orow = m0 + (lane >> 4) * 4;
    #pragma unroll
    for (int t = 0; t < 4; ++t) {
        const int col = t * 16 + nr;
        const float bb = bn[col];
        #pragma unroll
        for (int i = 0; i < 4; ++i)
            out[(size_t)(orow + i) * 64 + col] = acc[t][i] + bb;
    }
}

extern "C" void kernel_launch(void* const* d_in, const int* in_sizes, int n_in,
                              void* d_out, int out_size, void* d_ws, size_t ws_size,
                              hipStream_t stream)
{
    const float* feat   = (const float*)d_in[0];
    const float* weight = (const float*)d_in[1];
    const int*   src    = (const int*)d_in[2];
    const int*   dst    = (const int*)d_in[3];
    const float* Wp     = (const float*)d_in[4];
    const float* bp     = (const float*)d_in[5];
    const float* Wn     = (const float*)d_in[6];
    const float* bn     = (const float*)d_in[7];
    float* out = (float*)d_out;

    char* ws = (char*)d_ws;
    size_t cur = 0;
    auto alloc = [&](size_t bytes) -> void* {
        cur = (cur + 255) & ~(size_t)255;
        void* p = ws + cur;
        cur += bytes;
        return p;
    };

    unsigned short* h   = (unsigned short*)alloc((size_t)NN * 256 * 2);
    int* degcur         = (int*)alloc((size_t)2 * NN * 4);   // deg | cursor, one memset
    int* deg    = degcur;
    int* cursor = degcur + NN;
    int* offs   = (int*)alloc((size_t)(NN + 1) * 4);
    int* bsum   = (int*)alloc(1024);
    int2* csr   = (int2*)alloc((size_t)NE * 8);
    unsigned short* x2b = (unsigned short*)alloc((size_t)NN * 256 * 2);
    unsigned short* wnb = (unsigned short*)alloc((size_t)64 * 320 * 2);
    (void)ws_size; (void)in_sizes; (void)n_in; (void)out_size;

    hipMemsetAsync(degcur, 0, (size_t)2 * NN * 4, stream);

    cvt_wn_kernel<<<80, 256, 0, stream>>>(Wn, wnb);
    pool_kernel<<<POOL_BLOCKS, 256, 0, stream>>>(feat, Wp, bp, h);
    count_kernel<<<(NE + 255) / 256, 256, 0, stream>>>(dst, deg);
    scan1<<<(NN + 255) / 256, 256, 0, stream>>>(deg, bsum);
    scan2<<<1, 256, 0, stream>>>(bsum, (NN + 255) / 256);
    scan3<<<(NN + 255) / 256, 256, 0, stream>>>(deg, bsum, offs);
    scatter_kernel<<<(NE + 255) / 256, 256, 0, stream>>>(src, dst, weight, offs, cursor, csr);
    gather_kernel<<<(NGROUP + 3) / 4, 256, 0, stream>>>(h, offs, csr, x2b);
    epi_mfma_kernel<<<(NTILE + 3) / 4, 256, 0, stream>>>(feat, x2b, wnb, bn, out);
}

// Round 4
// 208.609 us; speedup vs baseline: 1.9863x; 1.1749x over previous
//
#include <hip/hip_runtime.h>
#include <stdint.h>

#define NN 50000
#define NE 800000
#define NGROUP 12500          // NN/4
#define NTILE16 3125          // NN/16 M-tiles

typedef __attribute__((ext_vector_type(8))) short short8v;   // 8 bf16 (4 VGPRs)
typedef __attribute__((ext_vector_type(4))) float f32x4;

static __device__ __forceinline__ float bf2f(unsigned short u) {
    union { unsigned int i; float f; } v; v.i = ((unsigned int)u) << 16; return v.f;
}
static __device__ __forceinline__ unsigned short f2bf(float f) {
    union { float f; unsigned int i; } v; v.f = f;
    unsigned int x = v.i;
    x += 0x7fffu + ((x >> 16) & 1u);
    return (unsigned short)(x >> 16);
}
static __device__ __forceinline__ unsigned int pkbf(float lo, float hi) {
    return (unsigned int)f2bf(lo) | ((unsigned int)f2bf(hi) << 16);
}

// feat f32 -> bf16, 8 elems/thread
__global__ __launch_bounds__(256) void cvt_feat_kernel(const float* __restrict__ feat,
                                                       unsigned short* __restrict__ featb)
{
    int i = blockIdx.x * 256 + threadIdx.x;          // chunk of 8
    if (i >= NN * 64 / 8) return;
    const float4* fp = (const float4*)feat + (size_t)i * 2;
    float4 a = fp[0], b = fp[1];
    union { unsigned int u[4]; uint4 v; } o;
    o.u[0] = pkbf(a.x, a.y); o.u[1] = pkbf(a.z, a.w);
    o.u[2] = pkbf(b.x, b.y); o.u[3] = pkbf(b.z, b.w);
    ((uint4*)featb)[i] = o.v;
}

// weights -> bf16. wpb rows permuted to h-layout: col j <-> Wp row r=(j&3)*64+(j>>2)
__global__ __launch_bounds__(256) void cvt_w_kernel(
    const float* __restrict__ Wp, const float* __restrict__ bp,
    const float* __restrict__ Wn,
    unsigned short* __restrict__ wpb, float* __restrict__ bpp,
    unsigned short* __restrict__ wnb)
{
    int i = blockIdx.x * 256 + threadIdx.x;
    if (i < 64 * 320) wnb[i] = f2bf(Wn[i]);
    if (i < 256 * 64) {
        int j = i >> 6, k = i & 63;
        int r = ((j & 3) << 6) + (j >> 2);
        wpb[i] = f2bf(Wp[r * 64 + k]);
        if (k == 0) bpp[j] = bp[r];
    }
}

// pool via MFMA: h[16-node tile][256 ch] = featb @ wpb^T (+bias), h stored bf16
// mfma(wpb_frag, featb_frag): D row = channel-sub (lane>>4)*4+i, col = node lane&15
__global__ __launch_bounds__(256) void pool_mfma_kernel(
    const unsigned short* __restrict__ featb,   // [N][64] bf16
    const unsigned short* __restrict__ wpb,     // [256][64] bf16 (permuted rows)
    const float* __restrict__ bpp,              // [256] f32 (permuted)
    unsigned short* __restrict__ h)             // [N][256] bf16
{
    const int wave = threadIdx.x >> 6;
    const int lane = threadIdx.x & 63;
    const int tile = blockIdx.x * 4 + wave;
    if (tile >= NTILE16) return;
    const int n0 = tile * 16;
    const int nr = lane & 15;
    const int kq = (lane >> 4) * 8;

    short8v bfrag[2];
    #pragma unroll
    for (int s = 0; s < 2; ++s)
        bfrag[s] = *(const short8v*)(featb + (size_t)(n0 + nr) * 64 + s * 32 + kq);

    f32x4 acc[16];
    #pragma unroll
    for (int t = 0; t < 16; ++t) acc[t] = (f32x4){0.f, 0.f, 0.f, 0.f};

    #pragma unroll
    for (int t = 0; t < 16; ++t) {
        #pragma unroll
        for (int s = 0; s < 2; ++s) {
            short8v a = *(const short8v*)(wpb + (size_t)(t * 16 + nr) * 64 + s * 32 + kq);
            acc[t] = __builtin_amdgcn_mfma_f32_16x16x32_bf16(a, bfrag[s], acc[t], 0, 0, 0);
        }
    }

    const int node = n0 + nr;
    const int csub = (lane >> 4) * 4;
    #pragma unroll
    for (int t = 0; t < 16; ++t) {
        const float4 bb = *(const float4*)(bpp + t * 16 + csub);
        uint2 pk;
        pk.x = pkbf(acc[t][0] + bb.x, acc[t][1] + bb.y);
        pk.y = pkbf(acc[t][2] + bb.z, acc[t][3] + bb.w);
        *(uint2*)(h + (size_t)node * 256 + t * 16 + csub) = pk;
    }
}

__global__ __launch_bounds__(256) void count_kernel(const int* __restrict__ dst,
                                                    int* __restrict__ deg)
{
    int e = blockIdx.x * 256 + threadIdx.x;
    if (e < NE) atomicAdd(&deg[dst[e]], 1);
}

__global__ __launch_bounds__(256) void scan1(const int* __restrict__ deg, int* __restrict__ bsum)
{
    __shared__ int s[256];
    int t = threadIdx.x;
    int i = blockIdx.x * 256 + t;
    s[t] = (i < NN) ? deg[i] : 0;
    __syncthreads();
    for (int off = 128; off > 0; off >>= 1) {
        if (t < off) s[t] += s[t + off];
        __syncthreads();
    }
    if (t == 0) bsum[blockIdx.x] = s[0];
}

__global__ __launch_bounds__(256) void scan2(int* __restrict__ bsum, int nb)
{
    __shared__ int s[256];
    int t = threadIdx.x;
    int v = (t < nb) ? bsum[t] : 0;
    s[t] = v;
    __syncthreads();
    for (int off = 1; off < 256; off <<= 1) {
        int add = (t >= off) ? s[t - off] : 0;
        __syncthreads();
        s[t] += add;
        __syncthreads();
    }
    if (t < nb) bsum[t] = s[t] - v;   // exclusive
}

__global__ __launch_bounds__(256) void scan3(const int* __restrict__ deg,
                                             const int* __restrict__ bsum,
                                             int* __restrict__ offs)
{
    __shared__ int s[256];
    int t = threadIdx.x;
    int i = blockIdx.x * 256 + t;
    int v = (i < NN) ? deg[i] : 0;
    s[t] = v;
    __syncthreads();
    for (int off = 1; off < 256; off <<= 1) {
        int add = (t >= off) ? s[t - off] : 0;
        __syncthreads();
        s[t] += add;
        __syncthreads();
    }
    if (i < NN) offs[i] = bsum[blockIdx.x] + s[t] - v;
    if (blockIdx.x == 0 && t == 0) offs[NN] = NE;
}

__global__ __launch_bounds__(256) void scatter_kernel(
    const int* __restrict__ src, const int* __restrict__ dst,
    const float* __restrict__ w, const int* __restrict__ offs,
    int* __restrict__ cursor, int2* __restrict__ csr)
{
    int e = blockIdx.x * 256 + threadIdx.x;
    if (e < NE) {
        int d = dst[e];
        int p = offs[d] + atomicAdd(&cursor[d], 1);
        csr[p] = make_int2(src[e], __float_as_int(w[e]));
    }
}

// gather: no LDS, 4 waves/block, each wave owns 4 nodes. 8-deep load pipeline.
// writes finalized stats x2b[n][256] = [sum | mean | max | std] bf16
__global__ __launch_bounds__(256) void gather_kernel(
    const unsigned short* __restrict__ h,   // [N][64][4] bf16
    const int* __restrict__ offs,
    const int2* __restrict__ csr,
    unsigned short* __restrict__ x2b)       // [N][256] bf16
{
    const int wave = threadIdx.x >> 6;
    const int lane = threadIdx.x & 63;
    const int g = blockIdx.x * 4 + wave;
    if (g >= NGROUP) return;
    const int n0 = g * 4;
    const ushort4* h4 = (const ushort4*)h;   // [N][64] of ushort4

    float s0[4], s1[4], s3[4], s2[4], vmx[4];
    #pragma unroll
    for (int nb = 0; nb < 4; ++nb) { s0[nb]=0.f; s1[nb]=0.f; s3[nb]=0.f; s2[nb]=0.f; vmx[nb]=-INFINITY; }

    #pragma unroll
    for (int nb = 0; nb < 4; ++nb) {
        const int n = n0 + nb;
        const int rs = offs[n], re = offs[n + 1];
        for (int base = rs; base < re; base += 64) {
            const int cnt = min(64, re - base);
            int sl = 0; int wli = 0;
            if (lane < cnt) {
                int2 ew = csr[base + lane];
                sl = ew.x; wli = ew.y;
            }
            int jj = 0;
            for (; jj + 8 <= cnt; jj += 8) {
                ushort4 hv[8];
                #pragma unroll
                for (int u = 0; u < 8; ++u) {
                    int sj = __builtin_amdgcn_readlane(sl, jj + u);
                    hv[u] = h4[(size_t)sj * 64 + lane];
                }
                #pragma unroll
                for (int u = 0; u < 8; ++u) {
                    float wj = __int_as_float(__builtin_amdgcn_readlane(wli, jj + u));
                    float a  = bf2f(hv[u].x);
                    float bm = bf2f(hv[u].y);
                    float mx = bf2f(hv[u].z);
                    float sd = bf2f(hv[u].w);
                    s0[nb] = fmaf(wj, a, s0[nb]);
                    s1[nb] = fmaf(wj, bm, s1[nb]);
                    vmx[nb] = fmaxf(vmx[nb], wj * mx);
                    s3[nb] = fmaf(wj, sd, s3[nb]);
                    s2[nb] = fmaf(wj * sd, sd, s2[nb]);
                }
            }
            for (; jj < cnt; ++jj) {
                int   sj = __builtin_amdgcn_readlane(sl, jj);
                float wj = __int_as_float(__builtin_amdgcn_readlane(wli, jj));
                ushort4 hv = h4[(size_t)sj * 64 + lane];
                float a  = bf2f(hv.x);
                float bm = bf2f(hv.y);
                float mx = bf2f(hv.z);
                float sd = bf2f(hv.w);
                s0[nb] = fmaf(wj, a, s0[nb]);
                s1[nb] = fmaf(wj, bm, s1[nb]);
                vmx[nb] = fmaxf(vmx[nb], wj * mx);
                s3[nb] = fmaf(wj, sd, s3[nb]);
                s2[nb] = fmaf(wj * sd, sd, s2[nb]);
            }
        }
    }

    #pragma unroll
    for (int nb = 0; nb < 4; ++nb) {
        const int n = n0 + nb;
        const int dg = offs[n + 1] - offs[n];
        float fsum, fmean, fmx, fstd;
        if (dg == 0) { fsum = fmean = fmx = fstd = 0.f; }
        else {
            const float inv = 1.0f / (float)dg;
            fsum  = s0[nb];
            fmean = s1[nb] * inv;
            fmx   = vmx[nb];
            const float m1 = s3[nb] * inv;
            const float m2 = s2[nb] * inv;
            fstd  = m2 - m1 * m1;
        }
        unsigned short* xp = x2b + (size_t)n * 256;
        xp[lane]       = f2bf(fsum);
        xp[64  + lane] = f2bf(fmean);
        xp[128 + lane] = f2bf(fmx);
        xp[192 + lane] = f2bf(fstd);
    }
}

// MFMA epilogue: out[50000x64] = [featb | x2b] (50000x320) @ WnT(320x64) + bn
__global__ __launch_bounds__(256) void epi_mfma_kernel(
    const unsigned short* __restrict__ featb,// [N][64] bf16
    const unsigned short* __restrict__ x2b,  // [N][256] bf16
    const unsigned short* __restrict__ wnb,  // [64][320] bf16
    const float* __restrict__ bn,
    float* __restrict__ out)
{
    const int wave = threadIdx.x >> 6;
    const int lane = threadIdx.x & 63;
    const int tile = blockIdx.x * 4 + wave;
    if (tile >= NTILE16) return;
    const int m0  = tile * 16;
    const int row = m0 + (lane & 15);
    const int kq  = (lane >> 4) * 8;
    const int nr  = lane & 15;

    f32x4 acc[4];
    #pragma unroll
    for (int t = 0; t < 4; ++t) acc[t] = (f32x4){0.f, 0.f, 0.f, 0.f};

    const short8v* wn8 = (const short8v*)wnb;   // [64][40] of short8

    #pragma unroll
    for (int s = 0; s < 2; ++s) {
        short8v a = *(const short8v*)(featb + (size_t)row * 64 + s * 32 + kq);
        #pragma unroll
        for (int t = 0; t < 4; ++t) {
            short8v b = wn8[((t * 16 + nr) * 320 + s * 32 + kq) >> 3];
            acc[t] = __builtin_amdgcn_mfma_f32_16x16x32_bf16(a, b, acc[t], 0, 0, 0);
        }
    }
    #pragma unroll
    for (int s = 2; s < 10; ++s) {
        short8v a = *(const short8v*)(x2b + (size_t)row * 256 + (s - 2) * 32 + kq);
        #pragma unroll
        for (int t = 0; t < 4; ++t) {
            short8v b = wn8[((t * 16 + nr) * 320 + s * 32 + kq) >> 3];
            acc[t] = __builtin_amdgcn_mfma_f32_16x16x32_bf16(a, b, acc[t], 0, 0, 0);
        }
    }

    const int orow = m0 + (lane >> 4) * 4;
    #pragma unroll
    for (int t = 0; t < 4; ++t) {
        const int col = t * 16 + nr;
        const float bb = bn[col];
        #pragma unroll
        for (int i = 0; i < 4; ++i)
            out[(size_t)(orow + i) * 64 + col] = acc[t][i] + bb;
    }
}

extern "C" void kernel_launch(void* const* d_in, const int* in_sizes, int n_in,
                              void* d_out, int out_size, void* d_ws, size_t ws_size,
                              hipStream_t stream)
{
    const float* feat   = (const float*)d_in[0];
    const float* weight = (const float*)d_in[1];
    const int*   src    = (const int*)d_in[2];
    const int*   dst    = (const int*)d_in[3];
    const float* Wp     = (const float*)d_in[4];
    const float* bp     = (const float*)d_in[5];
    const float* Wn     = (const float*)d_in[6];
    const float* bn     = (const float*)d_in[7];
    float* out = (float*)d_out;

    char* ws = (char*)d_ws;
    size_t cur = 0;
    auto alloc = [&](size_t bytes) -> void* {
        cur = (cur + 255) & ~(size_t)255;
        void* p = ws + cur;
        cur += bytes;
        return p;
    };

    unsigned short* h    = (unsigned short*)alloc((size_t)NN * 256 * 2);
    int* degcur          = (int*)alloc((size_t)2 * NN * 4);   // deg | cursor, one memset
    int* deg    = degcur;
    int* cursor = degcur + NN;
    int* offs   = (int*)alloc((size_t)(NN + 1) * 4);
    int* bsum   = (int*)alloc(1024);
    int2* csr   = (int2*)alloc((size_t)NE * 8);
    unsigned short* x2b  = (unsigned short*)alloc((size_t)NN * 256 * 2);
    unsigned short* featb= (unsigned short*)alloc((size_t)NN * 64 * 2);
    unsigned short* wnb  = (unsigned short*)alloc((size_t)64 * 320 * 2);
    unsigned short* wpb  = (unsigned short*)alloc((size_t)256 * 64 * 2);
    float* bpp           = (float*)alloc((size_t)256 * 4);
    (void)ws_size; (void)in_sizes; (void)n_in; (void)out_size;

    hipMemsetAsync(degcur, 0, (size_t)2 * NN * 4, stream);

    cvt_feat_kernel<<<(NN * 64 / 8 + 255) / 256, 256, 0, stream>>>(feat, featb);
    cvt_w_kernel<<<80, 256, 0, stream>>>(Wp, bp, Wn, wpb, bpp, wnb);
    pool_mfma_kernel<<<(NTILE16 + 3) / 4, 256, 0, stream>>>(featb, wpb, bpp, h);
    count_kernel<<<(NE + 255) / 256, 256, 0, stream>>>(dst, deg);
    scan1<<<(NN + 255) / 256, 256, 0, stream>>>(deg, bsum);
    scan2<<<1, 256, 0, stream>>>(bsum, (NN + 255) / 256);
    scan3<<<(NN + 255) / 256, 256, 0, stream>>>(deg, bsum, offs);
    scatter_kernel<<<(NE + 255) / 256, 256, 0, stream>>>(src, dst, weight, offs, cursor, csr);
    gather_kernel<<<(NGROUP + 3) / 4, 256, 0, stream>>>(h, offs, csr, x2b);
    epi_mfma_kernel<<<(NTILE16 + 3) / 4, 256, 0, stream>>>(featb, x2b, wnb, bn, out);
}

// Round 5
// 187.343 us; speedup vs baseline: 2.2117x; 1.1135x over previous
//
#include <hip/hip_runtime.h>
#include <stdint.h>

#define NN 50000
#define NE 800000
#define NTILE16 3125          // NN/16 M-tiles
#define X2S 264               // padded LDS row stride (shorts) for x2

typedef __attribute__((ext_vector_type(8))) short short8v;   // 8 bf16 (4 VGPRs)
typedef __attribute__((ext_vector_type(4))) float f32x4;

static __device__ __forceinline__ float bf2f(unsigned short u) {
    union { unsigned int i; float f; } v; v.i = ((unsigned int)u) << 16; return v.f;
}
static __device__ __forceinline__ unsigned short f2bf(float f) {
    union { float f; unsigned int i; } v; v.f = f;
    unsigned int x = v.i;
    x += 0x7fffu + ((x >> 16) & 1u);
    return (unsigned short)(x >> 16);
}
static __device__ __forceinline__ unsigned int pkbf(float lo, float hi) {
    return (unsigned int)f2bf(lo) | ((unsigned int)f2bf(hi) << 16);
}

// feat f32 -> bf16, 8 elems/thread
__global__ __launch_bounds__(256) void cvt_feat_kernel(const float* __restrict__ feat,
                                                       unsigned short* __restrict__ featb)
{
    int i = blockIdx.x * 256 + threadIdx.x;          // chunk of 8
    if (i >= NN * 64 / 8) return;
    const float4* fp = (const float4*)feat + (size_t)i * 2;
    float4 a = fp[0], b = fp[1];
    union { unsigned int u[4]; uint4 v; } o;
    o.u[0] = pkbf(a.x, a.y); o.u[1] = pkbf(a.z, a.w);
    o.u[2] = pkbf(b.x, b.y); o.u[3] = pkbf(b.z, b.w);
    ((uint4*)featb)[i] = o.v;
}

// Build all weight tables:
//  wnb2[64][320]: [Wn_feat | Wn_sum@Wsum | Wn_mean@Wmean | Wn_max | Wn_std] bf16
//  wpb2[128][64]: pool B rows j=2c+q -> Wp row (2+q)*64+c   (h_max,h_std parts)
//  bpp2[128], wstdb[64][64] (Wp rows 192..255), u[64], v[64]
__global__ __launch_bounds__(256) void cvt_w_kernel(
    const float* __restrict__ Wp, const float* __restrict__ bp,
    const float* __restrict__ Wn,
    unsigned short* __restrict__ wnb2, unsigned short* __restrict__ wpb2,
    float* __restrict__ bpp2, unsigned short* __restrict__ wstdb,
    float* __restrict__ uvec, float* __restrict__ vvec)
{
    int i = blockIdx.x * 256 + threadIdx.x;
    if (i < 20480) {                         // wnb2
        int o = i / 320, k = i - o * 320;
        float val;
        if (k < 64) {
            val = Wn[o * 320 + k];
        } else if (k < 128) {                // sum part: Sum_c Wn[o][64+c]*Wp[c][k-64]
            int kk = k - 64; float s = 0.f;
            for (int c = 0; c < 64; ++c) s += Wn[o * 320 + 64 + c] * Wp[c * 64 + kk];
            val = s;
        } else if (k < 192) {                // mean part: Sum_c Wn[o][128+c]*Wp[64+c][k-128]
            int kk = k - 128; float s = 0.f;
            for (int c = 0; c < 64; ++c) s += Wn[o * 320 + 128 + c] * Wp[(64 + c) * 64 + kk];
            val = s;
        } else {
            val = Wn[o * 320 + k];           // max/std parts: direct
        }
        wnb2[i] = f2bf(val);
    } else if (i < 28672) {                  // wpb2
        int idx = i - 20480;
        int j = idx >> 6, k = idx & 63;
        int r = (2 + (j & 1)) * 64 + (j >> 1);
        wpb2[idx] = f2bf(Wp[r * 64 + k]);
        if (k == 0) bpp2[j] = bp[r];
    } else if (i < 32768) {                  // wstdb
        int idx = i - 28672;
        int c = idx >> 6, k = idx & 63;
        wstdb[idx] = f2bf(Wp[(192 + c) * 64 + k]);
    } else if (i < 32896) {                  // u, v
        int j = i - 32768;
        if (j < 64) {
            float s = 0.f;
            for (int c = 0; c < 64; ++c) s += Wn[j * 320 + 64 + c] * bp[c];
            uvec[j] = s;
        } else {
            int o = j - 64; float s = 0.f;
            for (int c = 0; c < 64; ++c) s += Wn[o * 320 + 128 + c] * bp[64 + c];
            vvec[o] = s;
        }
    }
}

// pool via MFMA: hms[node][128] = interleaved (h_max[c], h_std[c]) bf16
__global__ __launch_bounds__(256) void pool_mfma_kernel(
    const unsigned short* __restrict__ featb,   // [N][64] bf16
    const unsigned short* __restrict__ wpb2,    // [128][64] bf16
    const float* __restrict__ bpp2,             // [128]
    unsigned short* __restrict__ hms)           // [N][128] bf16
{
    const int wave = threadIdx.x >> 6;
    const int lane = threadIdx.x & 63;
    const int tile = blockIdx.x * 4 + wave;
    if (tile >= NTILE16) return;
    const int n0 = tile * 16;
    const int nr = lane & 15;
    const int kq = (lane >> 4) * 8;

    short8v bfrag[2];
    #pragma unroll
    for (int s = 0; s < 2; ++s)
        bfrag[s] = *(const short8v*)(featb + (size_t)(n0 + nr) * 64 + s * 32 + kq);

    f32x4 acc[8];
    #pragma unroll
    for (int t = 0; t < 8; ++t) acc[t] = (f32x4){0.f, 0.f, 0.f, 0.f};

    #pragma unroll
    for (int t = 0; t < 8; ++t) {
        #pragma unroll
        for (int s = 0; s < 2; ++s) {
            short8v a = *(const short8v*)(wpb2 + (size_t)(t * 16 + nr) * 64 + s * 32 + kq);
            acc[t] = __builtin_amdgcn_mfma_f32_16x16x32_bf16(a, bfrag[s], acc[t], 0, 0, 0);
        }
    }

    const int node = n0 + nr;
    const int csub = (lane >> 4) * 4;
    #pragma unroll
    for (int t = 0; t < 8; ++t) {
        const float4 bb = *(const float4*)(bpp2 + t * 16 + csub);
        uint2 pk;
        pk.x = pkbf(acc[t][0] + bb.x, acc[t][1] + bb.y);
        pk.y = pkbf(acc[t][2] + bb.z, acc[t][3] + bb.w);
        *(uint2*)(hms + (size_t)node * 128 + t * 16 + csub) = pk;
    }
}

__global__ __launch_bounds__(256) void count_kernel(const int* __restrict__ dst,
                                                    int* __restrict__ deg)
{
    int e = blockIdx.x * 256 + threadIdx.x;
    if (e < NE) atomicAdd(&deg[dst[e]], 1);
}

__global__ __launch_bounds__(256) void scan1(const int* __restrict__ deg, int* __restrict__ bsum)
{
    __shared__ int s[256];
    int t = threadIdx.x;
    int i = blockIdx.x * 256 + t;
    s[t] = (i < NN) ? deg[i] : 0;
    __syncthreads();
    for (int off = 128; off > 0; off >>= 1) {
        if (t < off) s[t] += s[t + off];
        __syncthreads();
    }
    if (t == 0) bsum[blockIdx.x] = s[0];
}

__global__ __launch_bounds__(256) void scan2(int* __restrict__ bsum, int nb)
{
    __shared__ int s[256];
    int t = threadIdx.x;
    int v = (t < nb) ? bsum[t] : 0;
    s[t] = v;
    __syncthreads();
    for (int off = 1; off < 256; off <<= 1) {
        int add = (t >= off) ? s[t - off] : 0;
        __syncthreads();
        s[t] += add;
        __syncthreads();
    }
    if (t < nb) bsum[t] = s[t] - v;   // exclusive
}

__global__ __launch_bounds__(256) void scan3(const int* __restrict__ deg,
                                             const int* __restrict__ bsum,
                                             int* __restrict__ offs)
{
    __shared__ int s[256];
    int t = threadIdx.x;
    int i = blockIdx.x * 256 + t;
    int v = (i < NN) ? deg[i] : 0;
    s[t] = v;
    __syncthreads();
    for (int off = 1; off < 256; off <<= 1) {
        int add = (t >= off) ? s[t - off] : 0;
        __syncthreads();
        s[t] += add;
        __syncthreads();
    }
    if (i < NN) offs[i] = bsum[blockIdx.x] + s[t] - v;
    if (blockIdx.x == 0 && t == 0) offs[NN] = NE;
}

__global__ __launch_bounds__(256) void scatter_kernel(
    const int* __restrict__ src, const int* __restrict__ dst,
    const float* __restrict__ w, const int* __restrict__ offs,
    int* __restrict__ cursor, int2* __restrict__ csr)
{
    int e = blockIdx.x * 256 + threadIdx.x;
    if (e < NE) {
        int d = dst[e];
        int p = offs[d] + atomicAdd(&cursor[d], 1);
        csr[p] = make_int2(src[e], __float_as_int(w[e]));
    }
}

// fused gather + m1-GEMM + epilogue. Block = 4 waves = 16 nodes = one M-tile.
// Phase1: wave owns 4 nodes; lane=channel. g1 = sum w*feat, vmx = max(w*hmax),
//         s2 = sum w*hstd^2, sw = sum w.  Stage to LDS x2 rows:
//         [g1 | g1/deg | agg_max | agg_std(later)] bf16, stride X2S.
// Phase2: m1 = (g1@Wstd^T + sw*b_std)/deg via MFMA; agg_std = s2/deg - m1^2.
// Phase3: out = [featb | x2] @ wnb2^T + bn + sw*u + (sw/deg)*v
__global__ __launch_bounds__(256) void fused_gather_epi_kernel(
    const unsigned short* __restrict__ featb,   // [N][64]
    const unsigned short* __restrict__ hms,     // [N][128]
    const int* __restrict__ offs,
    const int2* __restrict__ csr,
    const unsigned short* __restrict__ wstdb,   // [64][64]
    const unsigned short* __restrict__ wnb2,    // [64][320]
    const float* __restrict__ bp,
    const float* __restrict__ bn,
    const float* __restrict__ uvec,
    const float* __restrict__ vvec,
    float* __restrict__ out)
{
    __shared__ unsigned short x2[16 * X2S];
    __shared__ float s2f[16][64];
    __shared__ float swl[16], invl[16];

    const int wave = threadIdx.x >> 6;
    const int lane = threadIdx.x & 63;
    const int n0 = blockIdx.x * 16;

    // ---- phase 1: gather ----
    float g1[4], vmx[4], s2[4], sw[4];
    #pragma unroll
    for (int nb = 0; nb < 4; ++nb) { g1[nb]=0.f; vmx[nb]=-INFINITY; s2[nb]=0.f; sw[nb]=0.f; }

    #pragma unroll
    for (int nb = 0; nb < 4; ++nb) {
        const int n = n0 + wave * 4 + nb;
        const int rs = offs[n], re = offs[n + 1];
        for (int base = rs; base < re; base += 64) {
            const int cnt = min(64, re - base);
            int sl = 0; int wli = 0;
            if (lane < cnt) {
                int2 ew = csr[base + lane];
                sl = ew.x; wli = ew.y;
            }
            int jj = 0;
            for (; jj + 8 <= cnt; jj += 8) {
                unsigned short fv[8]; unsigned int hv[8];
                #pragma unroll
                for (int u = 0; u < 8; ++u) {
                    int sj = __builtin_amdgcn_readlane(sl, jj + u);
                    fv[u] = featb[(size_t)sj * 64 + lane];
                    hv[u] = *(const unsigned int*)(hms + (size_t)sj * 128 + 2 * lane);
                }
                #pragma unroll
                for (int u = 0; u < 8; ++u) {
                    float wj = __int_as_float(__builtin_amdgcn_readlane(wli, jj + u));
                    float f  = bf2f(fv[u]);
                    float hm = bf2f((unsigned short)(hv[u] & 0xffffu));
                    float hs = bf2f((unsigned short)(hv[u] >> 16));
                    g1[nb] = fmaf(wj, f, g1[nb]);
                    vmx[nb] = fmaxf(vmx[nb], wj * hm);
                    s2[nb] = fmaf(wj * hs, hs, s2[nb]);
                    sw[nb] += wj;
                }
            }
            for (; jj < cnt; ++jj) {
                int   sj = __builtin_amdgcn_readlane(sl, jj);
                float wj = __int_as_float(__builtin_amdgcn_readlane(wli, jj));
                unsigned short fvu = featb[(size_t)sj * 64 + lane];
                unsigned int hvu = *(const unsigned int*)(hms + (size_t)sj * 128 + 2 * lane);
                float f  = bf2f(fvu);
                float hm = bf2f((unsigned short)(hvu & 0xffffu));
                float hs = bf2f((unsigned short)(hvu >> 16));
                g1[nb] = fmaf(wj, f, g1[nb]);
                vmx[nb] = fmaxf(vmx[nb], wj * hm);
                s2[nb] = fmaf(wj * hs, hs, s2[nb]);
                sw[nb] += wj;
            }
        }
    }

    #pragma unroll
    for (int nb = 0; nb < 4; ++nb) {
        const int node = wave * 4 + nb;
        const int n = n0 + node;
        const int dg = offs[n + 1] - offs[n];
        const float inv = 1.0f / (float)max(dg, 1);
        unsigned short* row = x2 + node * X2S;
        row[lane]       = f2bf(g1[nb]);
        row[64 + lane]  = f2bf(g1[nb] * inv);
        row[128 + lane] = f2bf(dg > 0 ? vmx[nb] : 0.f);
        s2f[node][lane] = s2[nb] * inv;
        if (lane == 0) { swl[node] = sw[nb]; invl[node] = inv; }
    }
    __syncthreads();

    // ---- phase 2: m1 GEMM + agg_std ----
    const int nr = lane & 15;
    const int kq = (lane >> 4) * 8;
    const int col = wave * 16 + nr;
    const int orow = (lane >> 4) * 4;
    {
        f32x4 m1acc = (f32x4){0.f, 0.f, 0.f, 0.f};
        #pragma unroll
        for (int s = 0; s < 2; ++s) {
            short8v a = *(const short8v*)(x2 + nr * X2S + s * 32 + kq);
            short8v b = *(const short8v*)(wstdb + (size_t)col * 64 + s * 32 + kq);
            m1acc = __builtin_amdgcn_mfma_f32_16x16x32_bf16(a, b, m1acc, 0, 0, 0);
        }
        const float bstd = bp[192 + col];
        #pragma unroll
        for (int i = 0; i < 4; ++i) {
            const int node = orow + i;
            const float m1 = (m1acc[i] + swl[node] * bstd) * invl[node];
            const float astd = s2f[node][col] - m1 * m1;
            x2[node * X2S + 192 + col] = f2bf(astd);
        }
    }
    __syncthreads();

    // ---- phase 3: epilogue, wave = col-tile ----
    f32x4 acc = (f32x4){0.f, 0.f, 0.f, 0.f};
    #pragma unroll
    for (int s = 0; s < 2; ++s) {
        short8v a = *(const short8v*)(featb + (size_t)(n0 + nr) * 64 + s * 32 + kq);
        short8v b = *(const short8v*)(wnb2 + (size_t)col * 320 + s * 32 + kq);
        acc = __builtin_amdgcn_mfma_f32_16x16x32_bf16(a, b, acc, 0, 0, 0);
    }
    #pragma unroll
    for (int s = 2; s < 10; ++s) {
        short8v a = *(const short8v*)(x2 + nr * X2S + (s - 2) * 32 + kq);
        short8v b = *(const short8v*)(wnb2 + (size_t)col * 320 + s * 32 + kq);
        acc = __builtin_amdgcn_mfma_f32_16x16x32_bf16(a, b, acc, 0, 0, 0);
    }

    const float bb = bn[col], uu = uvec[col], vv = vvec[col];
    #pragma unroll
    for (int i = 0; i < 4; ++i) {
        const int node = orow + i;
        const float o = acc[i] + bb + swl[node] * uu + swl[node] * invl[node] * vv;
        out[(size_t)(n0 + node) * 64 + col] = o;
    }
}

extern "C" void kernel_launch(void* const* d_in, const int* in_sizes, int n_in,
                              void* d_out, int out_size, void* d_ws, size_t ws_size,
                              hipStream_t stream)
{
    const float* feat   = (const float*)d_in[0];
    const float* weight = (const float*)d_in[1];
    const int*   src    = (const int*)d_in[2];
    const int*   dst    = (const int*)d_in[3];
    const float* Wp     = (const float*)d_in[4];
    const float* bp     = (const float*)d_in[5];
    const float* Wn     = (const float*)d_in[6];
    const float* bn     = (const float*)d_in[7];
    float* out = (float*)d_out;

    char* ws = (char*)d_ws;
    size_t cur = 0;
    auto alloc = [&](size_t bytes) -> void* {
        cur = (cur + 255) & ~(size_t)255;
        void* p = ws + cur;
        cur += bytes;
        return p;
    };

    unsigned short* hms  = (unsigned short*)alloc((size_t)NN * 128 * 2);
    int* degcur          = (int*)alloc((size_t)2 * NN * 4);   // deg | cursor, one memset
    int* deg    = degcur;
    int* cursor = degcur + NN;
    int* offs   = (int*)alloc((size_t)(NN + 1) * 4);
    int* bsum   = (int*)alloc(1024);
    int2* csr   = (int2*)alloc((size_t)NE * 8);
    unsigned short* featb= (unsigned short*)alloc((size_t)NN * 64 * 2);
    unsigned short* wnb2 = (unsigned short*)alloc((size_t)64 * 320 * 2);
    unsigned short* wpb2 = (unsigned short*)alloc((size_t)128 * 64 * 2);
    unsigned short* wstdb= (unsigned short*)alloc((size_t)64 * 64 * 2);
    float* bpp2          = (float*)alloc((size_t)128 * 4);
    float* uvec          = (float*)alloc((size_t)64 * 4);
    float* vvec          = (float*)alloc((size_t)64 * 4);
    (void)ws_size; (void)in_sizes; (void)n_in; (void)out_size;

    hipMemsetAsync(degcur, 0, (size_t)2 * NN * 4, stream);

    cvt_feat_kernel<<<(NN * 64 / 8 + 255) / 256, 256, 0, stream>>>(feat, featb);
    cvt_w_kernel<<<(32896 + 255) / 256, 256, 0, stream>>>(Wp, bp, Wn, wnb2, wpb2, bpp2, wstdb, uvec, vvec);
    pool_mfma_kernel<<<(NTILE16 + 3) / 4, 256, 0, stream>>>(featb, wpb2, bpp2, hms);
    count_kernel<<<(NE + 255) / 256, 256, 0, stream>>>(dst, deg);
    scan1<<<(NN + 255) / 256, 256, 0, stream>>>(deg, bsum);
    scan2<<<1, 256, 0, stream>>>(bsum, (NN + 255) / 256);
    scan3<<<(NN + 255) / 256, 256, 0, stream>>>(deg, bsum, offs);
    scatter_kernel<<<(NE + 255) / 256, 256, 0, stream>>>(src, dst, weight, offs, cursor, csr);
    fused_gather_epi_kernel<<<NTILE16, 256, 0, stream>>>(featb, hms, offs, csr, wstdb, wnb2,
                                                         bp, bn, uvec, vvec, out);
}

// Round 6
// 178.135 us; speedup vs baseline: 2.3261x; 1.0517x over previous
//
#include <hip/hip_runtime.h>
#include <stdint.h>

#define NN 50000
#define NE 800000
#define NTILE16 3125          // NN/16 M-tiles
#define X2S 264               // padded LDS row stride (shorts) for x2

typedef __attribute__((ext_vector_type(8))) short short8v;   // 8 bf16 (4 VGPRs)
typedef __attribute__((ext_vector_type(4))) float f32x4;

static __device__ __forceinline__ float bf2f(unsigned short u) {
    union { unsigned int i; float f; } v; v.i = ((unsigned int)u) << 16; return v.f;
}
static __device__ __forceinline__ float bf2f_lo(unsigned int u) {
    union { unsigned int i; float f; } v; v.i = u << 16; return v.f;
}
static __device__ __forceinline__ float bf2f_hi(unsigned int u) {
    union { unsigned int i; float f; } v; v.i = u & 0xffff0000u; return v.f;
}
static __device__ __forceinline__ unsigned short f2bf(float f) {
    union { float f; unsigned int i; } v; v.f = f;
    unsigned int x = v.i;
    x += 0x7fffu + ((x >> 16) & 1u);
    return (unsigned short)(x >> 16);
}
static __device__ __forceinline__ unsigned int pkbf(float lo, float hi) {
    return (unsigned int)f2bf(lo) | ((unsigned int)f2bf(hi) << 16);
}

// Build all weight tables:
//  wnb2[64][320]: [Wn_feat | Wn_sum@Wsum | Wn_mean@Wmean | Wn_max | Wn_std] bf16
//  wpb2[128][64]: pool B rows j=2c+q -> Wp row (2+q)*64+c   (h_max,h_std parts)
//  bpp2[128], wstdb[64][64] (Wp rows 192..255), u[64], v[64]
__global__ __launch_bounds__(256) void cvt_w_kernel(
    const float* __restrict__ Wp, const float* __restrict__ bp,
    const float* __restrict__ Wn,
    unsigned short* __restrict__ wnb2, unsigned short* __restrict__ wpb2,
    float* __restrict__ bpp2, unsigned short* __restrict__ wstdb,
    float* __restrict__ uvec, float* __restrict__ vvec)
{
    int i = blockIdx.x * 256 + threadIdx.x;
    if (i < 20480) {                         // wnb2
        int o = i / 320, k = i - o * 320;
        float val;
        if (k < 64) {
            val = Wn[o * 320 + k];
        } else if (k < 128) {                // sum part: Sum_c Wn[o][64+c]*Wp[c][k-64]
            int kk = k - 64; float s = 0.f;
            for (int c = 0; c < 64; ++c) s += Wn[o * 320 + 64 + c] * Wp[c * 64 + kk];
            val = s;
        } else if (k < 192) {                // mean part: Sum_c Wn[o][128+c]*Wp[64+c][k-128]
            int kk = k - 128; float s = 0.f;
            for (int c = 0; c < 64; ++c) s += Wn[o * 320 + 128 + c] * Wp[(64 + c) * 64 + kk];
            val = s;
        } else {
            val = Wn[o * 320 + k];           // max/std parts: direct
        }
        wnb2[i] = f2bf(val);
    } else if (i < 28672) {                  // wpb2
        int idx = i - 20480;
        int j = idx >> 6, k = idx & 63;
        int r = (2 + (j & 1)) * 64 + (j >> 1);
        wpb2[idx] = f2bf(Wp[r * 64 + k]);
        if (k == 0) bpp2[j] = bp[r];
    } else if (i < 32768) {                  // wstdb
        int idx = i - 28672;
        int c = idx >> 6, k = idx & 63;
        wstdb[idx] = f2bf(Wp[(192 + c) * 64 + k]);
    } else if (i < 32896) {                  // u, v
        int j = i - 32768;
        if (j < 64) {
            float s = 0.f;
            for (int c = 0; c < 64; ++c) s += Wn[j * 320 + 64 + c] * bp[c];
            uvec[j] = s;
        } else {
            int o = j - 64; float s = 0.f;
            for (int c = 0; c < 64; ++c) s += Wn[o * 320 + 128 + c] * bp[64 + c];
            vvec[o] = s;
        }
    }
}

// pool via MFMA, with fused feat->bf16 conversion and fused degree count.
// hms[node][128] = interleaved (h_max[c], h_std[c]) bf16; featb[node][64] bf16.
__global__ __launch_bounds__(256) void pool_mfma_kernel(
    const float* __restrict__ feat,             // [N][64] f32
    const int* __restrict__ dstE,               // [E]
    int* __restrict__ deg,
    const unsigned short* __restrict__ wpb2,    // [128][64] bf16
    const float* __restrict__ bpp2,             // [128]
    unsigned short* __restrict__ featb,         // [N][64] bf16 (out)
    unsigned short* __restrict__ hms)           // [N][128] bf16 (out)
{
    // fused degree count: 200192 threads x 4 edges
    const int gtid = blockIdx.x * 256 + threadIdx.x;
    if (gtid < NE / 4) {
        int4 d4 = ((const int4*)dstE)[gtid];
        atomicAdd(&deg[d4.x], 1); atomicAdd(&deg[d4.y], 1);
        atomicAdd(&deg[d4.z], 1); atomicAdd(&deg[d4.w], 1);
    }

    const int wave = threadIdx.x >> 6;
    const int lane = threadIdx.x & 63;
    const int tile = blockIdx.x * 4 + wave;
    if (tile >= NTILE16) return;
    const int n0 = tile * 16;
    const int nr = lane & 15;
    const int kq = (lane >> 4) * 8;

    // load feat f32, convert to bf16 frag, and write featb
    short8v bfrag[2];
    #pragma unroll
    for (int s = 0; s < 2; ++s) {
        const float4* fp = (const float4*)(feat + (size_t)(n0 + nr) * 64 + s * 32 + kq);
        float4 a = fp[0], b = fp[1];
        union { unsigned int u[4]; short8v v; uint4 q; } au;
        au.u[0] = pkbf(a.x, a.y); au.u[1] = pkbf(a.z, a.w);
        au.u[2] = pkbf(b.x, b.y); au.u[3] = pkbf(b.z, b.w);
        bfrag[s] = au.v;
        *(uint4*)(featb + (size_t)(n0 + nr) * 64 + s * 32 + kq) = au.q;
    }

    f32x4 acc[8];
    #pragma unroll
    for (int t = 0; t < 8; ++t) acc[t] = (f32x4){0.f, 0.f, 0.f, 0.f};

    #pragma unroll
    for (int t = 0; t < 8; ++t) {
        #pragma unroll
        for (int s = 0; s < 2; ++s) {
            short8v a = *(const short8v*)(wpb2 + (size_t)(t * 16 + nr) * 64 + s * 32 + kq);
            acc[t] = __builtin_amdgcn_mfma_f32_16x16x32_bf16(a, bfrag[s], acc[t], 0, 0, 0);
        }
    }

    const int node = n0 + nr;
    const int csub = (lane >> 4) * 4;
    #pragma unroll
    for (int t = 0; t < 8; ++t) {
        const float4 bb = *(const float4*)(bpp2 + t * 16 + csub);
        uint2 pk;
        pk.x = pkbf(acc[t][0] + bb.x, acc[t][1] + bb.y);
        pk.y = pkbf(acc[t][2] + bb.z, acc[t][3] + bb.w);
        *(uint2*)(hms + (size_t)node * 128 + t * 16 + csub) = pk;
    }
}

__global__ __launch_bounds__(256) void scan1(const int* __restrict__ deg, int* __restrict__ bsum)
{
    __shared__ int s[256];
    int t = threadIdx.x;
    int i = blockIdx.x * 256 + t;
    s[t] = (i < NN) ? deg[i] : 0;
    __syncthreads();
    for (int off = 128; off > 0; off >>= 1) {
        if (t < off) s[t] += s[t + off];
        __syncthreads();
    }
    if (t == 0) bsum[blockIdx.x] = s[0];
}

__global__ __launch_bounds__(256) void scan2(int* __restrict__ bsum, int nb)
{
    __shared__ int s[256];
    int t = threadIdx.x;
    int v = (t < nb) ? bsum[t] : 0;
    s[t] = v;
    __syncthreads();
    for (int off = 1; off < 256; off <<= 1) {
        int add = (t >= off) ? s[t - off] : 0;
        __syncthreads();
        s[t] += add;
        __syncthreads();
    }
    if (t < nb) bsum[t] = s[t] - v;   // exclusive
}

__global__ __launch_bounds__(256) void scan3(const int* __restrict__ deg,
                                             const int* __restrict__ bsum,
                                             int* __restrict__ offs)
{
    __shared__ int s[256];
    int t = threadIdx.x;
    int i = blockIdx.x * 256 + t;
    int v = (i < NN) ? deg[i] : 0;
    s[t] = v;
    __syncthreads();
    for (int off = 1; off < 256; off <<= 1) {
        int add = (t >= off) ? s[t - off] : 0;
        __syncthreads();
        s[t] += add;
        __syncthreads();
    }
    if (i < NN) offs[i] = bsum[blockIdx.x] + s[t] - v;
    if (blockIdx.x == 0 && t == 0) offs[NN] = NE;
}

__global__ __launch_bounds__(256) void scatter_kernel(
    const int* __restrict__ src, const int* __restrict__ dst,
    const float* __restrict__ w, const int* __restrict__ offs,
    int* __restrict__ cursor, int2* __restrict__ csr)
{
    int e = blockIdx.x * 256 + threadIdx.x;
    if (e < NE) {
        int d = dst[e];
        int p = offs[d] + atomicAdd(&cursor[d], 1);
        csr[p] = make_int2(src[e], __float_as_int(w[e]));
    }
}

// fused gather + m1-GEMM + epilogue. Block = 4 waves = 16 nodes = one M-tile.
// Phase1 (2-edges/iteration): lanes 0-31 = edge subset A (2 channels/lane),
//   lanes 32-63 = edge subset B. Per node, edge list split at h=ceil(cnt/2).
//   8-deep unrolled groups, clamped+masked (no scalar tail), 16 loads in flight.
// Phase2: m1 = (g1@Wstd^T + sw*b_std)/deg via MFMA; agg_std = s2/deg - m1^2.
// Phase3: out = [featb | x2] @ wnb2^T + bn + sw*u + (sw/deg)*v
__global__ __launch_bounds__(256) void fused_gather_epi_kernel(
    const unsigned short* __restrict__ featb,   // [N][64]
    const unsigned short* __restrict__ hms,     // [N][128]
    const int* __restrict__ offs,
    const int2* __restrict__ csr,
    const unsigned short* __restrict__ wstdb,   // [64][64]
    const unsigned short* __restrict__ wnb2,    // [64][320]
    const float* __restrict__ bp,
    const float* __restrict__ bn,
    const float* __restrict__ uvec,
    const float* __restrict__ vvec,
    float* __restrict__ out)
{
    __shared__ unsigned short x2[16 * X2S];
    __shared__ float s2f[16][64];
    __shared__ float swl[16], invl[16];

    const int wave = threadIdx.x >> 6;
    const int lane = threadIdx.x & 63;
    const int half = lane >> 5;
    const int c2   = lane & 31;          // channel pair index: channels 2*c2, 2*c2+1
    const int n0 = blockIdx.x * 16;

    const unsigned int* featp = (const unsigned int*)featb;  // [N][32] uint
    const uint2*        hmsp  = (const uint2*)hms;           // [N][32] uint2

    // ---- phase 1: gather ----
    float g10[4], g11[4], vx0[4], vx1[4], s20[4], s21[4], swa[4];
    #pragma unroll
    for (int nb = 0; nb < 4; ++nb) {
        g10[nb]=0.f; g11[nb]=0.f; vx0[nb]=-INFINITY; vx1[nb]=-INFINITY;
        s20[nb]=0.f; s21[nb]=0.f; swa[nb]=0.f;
    }

    #pragma unroll
    for (int nb = 0; nb < 4; ++nb) {
        const int n = n0 + wave * 4 + nb;
        const int rs = offs[n], re = offs[n + 1];
        for (int base = rs; base < re; base += 64) {
            const int cnt = min(64, re - base);
            int sl = 0; int wli = 0;
            if (lane < cnt) {
                int2 ew = csr[base + lane];
                sl = ew.x; wli = ew.y;
            }
            const int h     = (cnt + 1) >> 1;
            const int hoff  = half ? h : 0;
            const int bound = half ? cnt : h;
            const int cm1   = cnt - 1;
            for (int jj = 0; jj < h; jj += 8) {
                unsigned int pf[8]; uint2 ph[8]; int ix[8];
                #pragma unroll
                for (int u = 0; u < 8; ++u) {
                    int gi = jj + u + hoff;
                    int ic = min(gi, cm1);
                    ix[u] = ic;
                    int sj = __shfl(sl, ic);
                    pf[u] = featp[(size_t)sj * 32 + c2];
                    ph[u] = hmsp[(size_t)sj * 32 + c2];
                }
                #pragma unroll
                for (int u = 0; u < 8; ++u) {
                    int gi = jj + u + hoff;
                    float wj = __int_as_float(__shfl(wli, ix[u]));
                    bool valid = gi < bound;
                    wj = valid ? wj : 0.f;
                    float f0 = bf2f_lo(pf[u]);
                    float f1 = bf2f_hi(pf[u]);
                    float hm0 = bf2f_lo(ph[u].x), hs0 = bf2f_hi(ph[u].x);
                    float hm1 = bf2f_lo(ph[u].y), hs1 = bf2f_hi(ph[u].y);
                    g10[nb] = fmaf(wj, f0, g10[nb]);
                    g11[nb] = fmaf(wj, f1, g11[nb]);
                    float m0 = valid ? wj * hm0 : -INFINITY;
                    float m1_ = valid ? wj * hm1 : -INFINITY;
                    vx0[nb] = fmaxf(vx0[nb], m0);
                    vx1[nb] = fmaxf(vx1[nb], m1_);
                    s20[nb] = fmaf(wj * hs0, hs0, s20[nb]);
                    s21[nb] = fmaf(wj * hs1, hs1, s21[nb]);
                    swa[nb] += wj;
                }
            }
        }
    }

    // cross-half combine + stage to LDS
    #pragma unroll
    for (int nb = 0; nb < 4; ++nb) {
        float a  = g10[nb] + __shfl_xor(g10[nb], 32);
        float b  = g11[nb] + __shfl_xor(g11[nb], 32);
        float v0 = fmaxf(vx0[nb], __shfl_xor(vx0[nb], 32));
        float v1 = fmaxf(vx1[nb], __shfl_xor(vx1[nb], 32));
        float q0 = s20[nb] + __shfl_xor(s20[nb], 32);
        float q1 = s21[nb] + __shfl_xor(s21[nb], 32);
        float sw = swa[nb] + __shfl_xor(swa[nb], 32);
        const int node = wave * 4 + nb;
        const int n = n0 + node;
        const int dg = offs[n + 1] - offs[n];
        const float inv = 1.0f / (float)max(dg, 1);
        if (half == 0) {
            unsigned short* row = x2 + node * X2S;
            *(unsigned int*)(row + 2 * c2)       = pkbf(a, b);
            *(unsigned int*)(row + 64 + 2 * c2)  = pkbf(a * inv, b * inv);
            *(unsigned int*)(row + 128 + 2 * c2) = pkbf(dg > 0 ? v0 : 0.f, dg > 0 ? v1 : 0.f);
            float2 qq; qq.x = q0 * inv; qq.y = q1 * inv;
            *(float2*)(&s2f[node][2 * c2]) = qq;
            if (c2 == 0) { swl[node] = sw; invl[node] = inv; }
        }
    }
    __syncthreads();

    // ---- phase 2: m1 GEMM + agg_std ----
    const int nr = lane & 15;
    const int kq = (lane >> 4) * 8;
    const int col = wave * 16 + nr;
    const int orow = (lane >> 4) * 4;
    {
        f32x4 m1acc = (f32x4){0.f, 0.f, 0.f, 0.f};
        #pragma unroll
        for (int s = 0; s < 2; ++s) {
            short8v a = *(const short8v*)(x2 + nr * X2S + s * 32 + kq);
            short8v b = *(const short8v*)(wstdb + (size_t)col * 64 + s * 32 + kq);
            m1acc = __builtin_amdgcn_mfma_f32_16x16x32_bf16(a, b, m1acc, 0, 0, 0);
        }
        const float bstd = bp[192 + col];
        #pragma unroll
        for (int i = 0; i < 4; ++i) {
            const int node = orow + i;
            const float m1 = (m1acc[i] + swl[node] * bstd) * invl[node];
            const float astd = s2f[node][col] - m1 * m1;
            x2[node * X2S + 192 + col] = f2bf(astd);
        }
    }
    __syncthreads();

    // ---- phase 3: epilogue, wave = col-tile ----
    f32x4 acc = (f32x4){0.f, 0.f, 0.f, 0.f};
    #pragma unroll
    for (int s = 0; s < 2; ++s) {
        short8v a = *(const short8v*)(featb + (size_t)(n0 + nr) * 64 + s * 32 + kq);
        short8v b = *(const short8v*)(wnb2 + (size_t)col * 320 + s * 32 + kq);
        acc = __builtin_amdgcn_mfma_f32_16x16x32_bf16(a, b, acc, 0, 0, 0);
    }
    #pragma unroll
    for (int s = 2; s < 10; ++s) {
        short8v a = *(const short8v*)(x2 + nr * X2S + (s - 2) * 32 + kq);
        short8v b = *(const short8v*)(wnb2 + (size_t)col * 320 + s * 32 + kq);
        acc = __builtin_amdgcn_mfma_f32_16x16x32_bf16(a, b, acc, 0, 0, 0);
    }

    const float bb = bn[col], uu = uvec[col], vv = vvec[col];
    #pragma unroll
    for (int i = 0; i < 4; ++i) {
        const int node = orow + i;
        const float o = acc[i] + bb + swl[node] * uu + swl[node] * invl[node] * vv;
        out[(size_t)(n0 + node) * 64 + col] = o;
    }
}

extern "C" void kernel_launch(void* const* d_in, const int* in_sizes, int n_in,
                              void* d_out, int out_size, void* d_ws, size_t ws_size,
                              hipStream_t stream)
{
    const float* feat   = (const float*)d_in[0];
    const float* weight = (const float*)d_in[1];
    const int*   src    = (const int*)d_in[2];
    const int*   dst    = (const int*)d_in[3];
    const float* Wp     = (const float*)d_in[4];
    const float* bp     = (const float*)d_in[5];
    const float* Wn     = (const float*)d_in[6];
    const float* bn     = (const float*)d_in[7];
    float* out = (float*)d_out;

    char* ws = (char*)d_ws;
    size_t cur = 0;
    auto alloc = [&](size_t bytes) -> void* {
        cur = (cur + 255) & ~(size_t)255;
        void* p = ws + cur;
        cur += bytes;
        return p;
    };

    unsigned short* hms  = (unsigned short*)alloc((size_t)NN * 128 * 2);
    int* degcur          = (int*)alloc((size_t)2 * NN * 4);   // deg | cursor, one memset
    int* deg    = degcur;
    int* cursor = degcur + NN;
    int* offs   = (int*)alloc((size_t)(NN + 1) * 4);
    int* bsum   = (int*)alloc(1024);
    int2* csr   = (int2*)alloc((size_t)NE * 8);
    unsigned short* featb= (unsigned short*)alloc((size_t)NN * 64 * 2);
    unsigned short* wnb2 = (unsigned short*)alloc((size_t)64 * 320 * 2);
    unsigned short* wpb2 = (unsigned short*)alloc((size_t)128 * 64 * 2);
    unsigned short* wstdb= (unsigned short*)alloc((size_t)64 * 64 * 2);
    float* bpp2          = (float*)alloc((size_t)128 * 4);
    float* uvec          = (float*)alloc((size_t)64 * 4);
    float* vvec          = (float*)alloc((size_t)64 * 4);
    (void)ws_size; (void)in_sizes; (void)n_in; (void)out_size;

    hipMemsetAsync(degcur, 0, (size_t)2 * NN * 4, stream);

    cvt_w_kernel<<<(32896 + 255) / 256, 256, 0, stream>>>(Wp, bp, Wn, wnb2, wpb2, bpp2, wstdb, uvec, vvec);
    pool_mfma_kernel<<<(NTILE16 + 3) / 4, 256, 0, stream>>>(feat, dst, deg, wpb2, bpp2, featb, hms);
    scan1<<<(NN + 255) / 256, 256, 0, stream>>>(deg, bsum);
    scan2<<<1, 256, 0, stream>>>(bsum, (NN + 255) / 256);
    scan3<<<(NN + 255) / 256, 256, 0, stream>>>(deg, bsum, offs);
    scatter_kernel<<<(NE + 255) / 256, 256, 0, stream>>>(src, dst, weight, offs, cursor, csr);
    fused_gather_epi_kernel<<<NTILE16, 256, 0, stream>>>(featb, hms, offs, csr, wstdb, wnb2,
                                                         bp, bn, uvec, vvec, out);
}

// Round 7
// 166.008 us; speedup vs baseline: 2.4960x; 1.0731x over previous
//
#include <hip/hip_runtime.h>
#include <stdint.h>

#define NN 50000
#define NE 800000
#define NTILE16 3125          // NN/16 M-tiles
#define X2S 264               // padded LDS row stride (shorts) for x2
#define NBLK 196              // (NN+255)/256 scan blocks

typedef __attribute__((ext_vector_type(8))) short short8v;   // 8 bf16 (4 VGPRs)
typedef __attribute__((ext_vector_type(4))) float f32x4;

static __device__ __forceinline__ float bf2f(unsigned short u) {
    union { unsigned int i; float f; } v; v.i = ((unsigned int)u) << 16; return v.f;
}
static __device__ __forceinline__ float bf2f_lo(unsigned int u) {
    union { unsigned int i; float f; } v; v.i = u << 16; return v.f;
}
static __device__ __forceinline__ float bf2f_hi(unsigned int u) {
    union { unsigned int i; float f; } v; v.i = u & 0xffff0000u; return v.f;
}
static __device__ __forceinline__ unsigned short f2bf(float f) {
    union { float f; unsigned int i; } v; v.f = f;
    unsigned int x = v.i;
    x += 0x7fffu + ((x >> 16) & 1u);
    return (unsigned short)(x >> 16);
}
static __device__ __forceinline__ unsigned int pkbf(float lo, float hi) {
    return (unsigned int)f2bf(lo) | ((unsigned int)f2bf(hi) << 16);
}

// Build weight tables + zero deg/cursor (fused memset).
//  wnb2[64][320]: [Wn_feat | Wn_sum@Wsum | Wn_mean@Wmean | Wn_max | Wn_std] bf16
//  wpb2[128][64]: pool B rows j=2c+q -> Wp row (2+q)*64+c   (h_max,h_std parts)
//  bpp2[128], u[64], v[64]
__global__ __launch_bounds__(256) void cvt_w_kernel(
    const float* __restrict__ Wp, const float* __restrict__ bp,
    const float* __restrict__ Wn,
    unsigned short* __restrict__ wnb2, unsigned short* __restrict__ wpb2,
    float* __restrict__ bpp2,
    float* __restrict__ uvec, float* __restrict__ vvec,
    int4* __restrict__ degzero)              // 2*NN ints = 25000 int4
{
    int i = blockIdx.x * 256 + threadIdx.x;
    if (i < 25000) degzero[i] = make_int4(0, 0, 0, 0);
    if (i < 20480) {                         // wnb2
        int o = i / 320, k = i - o * 320;
        float val;
        if (k < 64) {
            val = Wn[o * 320 + k];
        } else if (k < 128) {                // sum part
            int kk = k - 64; float s = 0.f;
            for (int c = 0; c < 64; ++c) s += Wn[o * 320 + 64 + c] * Wp[c * 64 + kk];
            val = s;
        } else if (k < 192) {                // mean part
            int kk = k - 128; float s = 0.f;
            for (int c = 0; c < 64; ++c) s += Wn[o * 320 + 128 + c] * Wp[(64 + c) * 64 + kk];
            val = s;
        } else {
            val = Wn[o * 320 + k];           // max/std parts: direct
        }
        wnb2[i] = f2bf(val);
    } else if (i < 28672) {                  // wpb2
        int idx = i - 20480;
        int j = idx >> 6, k = idx & 63;
        int r = (2 + (j & 1)) * 64 + (j >> 1);
        wpb2[idx] = f2bf(Wp[r * 64 + k]);
        if (k == 0) bpp2[j] = bp[r];
    } else if (i < 28800) {                  // u, v
        int j = i - 28672;
        if (j < 64) {
            float s = 0.f;
            for (int c = 0; c < 64; ++c) s += Wn[j * 320 + 64 + c] * bp[c];
            uvec[j] = s;
        } else {
            int o = j - 64; float s = 0.f;
            for (int c = 0; c < 64; ++c) s += Wn[o * 320 + 128 + c] * bp[64 + c];
            vvec[o] = s;
        }
    }
}

// pool via MFMA, with fused feat->bf16 conversion and fused degree count.
__global__ __launch_bounds__(256) void pool_mfma_kernel(
    const float* __restrict__ feat,             // [N][64] f32
    const int* __restrict__ dstE,               // [E]
    int* __restrict__ deg,
    const unsigned short* __restrict__ wpb2,    // [128][64] bf16
    const float* __restrict__ bpp2,             // [128]
    unsigned short* __restrict__ featb,         // [N][64] bf16 (out)
    unsigned short* __restrict__ hms)           // [N][128] bf16 (out)
{
    const int gtid = blockIdx.x * 256 + threadIdx.x;
    if (gtid < NE / 4) {
        int4 d4 = ((const int4*)dstE)[gtid];
        atomicAdd(&deg[d4.x], 1); atomicAdd(&deg[d4.y], 1);
        atomicAdd(&deg[d4.z], 1); atomicAdd(&deg[d4.w], 1);
    }

    const int wave = threadIdx.x >> 6;
    const int lane = threadIdx.x & 63;
    const int tile = blockIdx.x * 4 + wave;
    if (tile >= NTILE16) return;
    const int n0 = tile * 16;
    const int nr = lane & 15;
    const int kq = (lane >> 4) * 8;

    short8v bfrag[2];
    #pragma unroll
    for (int s = 0; s < 2; ++s) {
        const float4* fp = (const float4*)(feat + (size_t)(n0 + nr) * 64 + s * 32 + kq);
        float4 a = fp[0], b = fp[1];
        union { unsigned int u[4]; short8v v; uint4 q; } au;
        au.u[0] = pkbf(a.x, a.y); au.u[1] = pkbf(a.z, a.w);
        au.u[2] = pkbf(b.x, b.y); au.u[3] = pkbf(b.z, b.w);
        bfrag[s] = au.v;
        *(uint4*)(featb + (size_t)(n0 + nr) * 64 + s * 32 + kq) = au.q;
    }

    f32x4 acc[8];
    #pragma unroll
    for (int t = 0; t < 8; ++t) acc[t] = (f32x4){0.f, 0.f, 0.f, 0.f};

    #pragma unroll
    for (int t = 0; t < 8; ++t) {
        #pragma unroll
        for (int s = 0; s < 2; ++s) {
            short8v a = *(const short8v*)(wpb2 + (size_t)(t * 16 + nr) * 64 + s * 32 + kq);
            acc[t] = __builtin_amdgcn_mfma_f32_16x16x32_bf16(a, bfrag[s], acc[t], 0, 0, 0);
        }
    }

    const int node = n0 + nr;
    const int csub = (lane >> 4) * 4;
    #pragma unroll
    for (int t = 0; t < 8; ++t) {
        const float4 bb = *(const float4*)(bpp2 + t * 16 + csub);
        uint2 pk;
        pk.x = pkbf(acc[t][0] + bb.x, acc[t][1] + bb.y);
        pk.y = pkbf(acc[t][2] + bb.z, acc[t][3] + bb.w);
        *(uint2*)(hms + (size_t)node * 128 + t * 16 + csub) = pk;
    }
}

__global__ __launch_bounds__(256) void scan1(const int* __restrict__ deg, int* __restrict__ bsum)
{
    __shared__ int s[256];
    int t = threadIdx.x;
    int i = blockIdx.x * 256 + t;
    s[t] = (i < NN) ? deg[i] : 0;
    __syncthreads();
    for (int off = 128; off > 0; off >>= 1) {
        if (t < off) s[t] += s[t + off];
        __syncthreads();
    }
    if (t == 0) bsum[blockIdx.x] = s[0];
}

// scan3 with inlined scan of the 196 block sums (removes scan2 launch)
__global__ __launch_bounds__(256) void scan3(const int* __restrict__ deg,
                                             const int* __restrict__ bsum,
                                             int* __restrict__ offs)
{
    __shared__ int sb[256];
    __shared__ int s[256];
    int t = threadIdx.x;
    int i = blockIdx.x * 256 + t;

    int bv = (t < NBLK) ? bsum[t] : 0;
    sb[t] = bv;
    __syncthreads();
    for (int off = 1; off < 256; off <<= 1) {
        int add = (t >= off) ? sb[t - off] : 0;
        __syncthreads();
        sb[t] += add;
        __syncthreads();
    }
    const int bpre = (blockIdx.x == 0) ? 0 : sb[blockIdx.x - 1];   // exclusive block prefix

    int v = (i < NN) ? deg[i] : 0;
    s[t] = v;
    __syncthreads();
    for (int off = 1; off < 256; off <<= 1) {
        int add = (t >= off) ? s[t - off] : 0;
        __syncthreads();
        s[t] += add;
        __syncthreads();
    }
    if (i < NN) offs[i] = bpre + s[t] - v;
    if (blockIdx.x == 0 && t == 0) offs[NN] = NE;
}

__global__ __launch_bounds__(256) void scatter_kernel(
    const int* __restrict__ src, const int* __restrict__ dst,
    const float* __restrict__ w, const int* __restrict__ offs,
    int* __restrict__ cursor, int2* __restrict__ csr)
{
    int e = blockIdx.x * 256 + threadIdx.x;
    if (e < NE) {
        int d = dst[e];
        int p = offs[d] + atomicAdd(&cursor[d], 1);
        csr[p] = make_int2(src[e], __float_as_int(w[e]));
    }
}

// fused gather + epilogue. Block = 8 waves = 16 nodes (2 nodes/wave).
// Phase1: lane=channel; per edge: scalar readlane broadcasts (uniform indices,
//   clamped groups of 8, no tail). Accumulate g1, vmx, s2, s3, sw.
//   astd computed in-lane; stage [g1 | g1/deg | max | std] bf16 to LDS.
// Phase2: epilogue on waves 0-3: out = [featb | x2] @ wnb2^T + bn + sw*u + (sw/deg)*v
__global__ __launch_bounds__(512) void fused_gather_epi_kernel(
    const unsigned short* __restrict__ featb,   // [N][64]
    const unsigned short* __restrict__ hms,     // [N][128]
    const int* __restrict__ offs,
    const int2* __restrict__ csr,
    const unsigned short* __restrict__ wnb2,    // [64][320]
    const float* __restrict__ bn,
    const float* __restrict__ uvec,
    const float* __restrict__ vvec,
    float* __restrict__ out)
{
    __shared__ unsigned short x2[16 * X2S];
    __shared__ float swl[16], invl[16];

    const int wave = threadIdx.x >> 6;
    const int lane = threadIdx.x & 63;
    const int n0 = blockIdx.x * 16;

    const unsigned int* hmsp = (const unsigned int*)hms;   // [N][64] uint (hmax,hstd)

    // ---- phase 1: gather, 2 nodes per wave ----
    #pragma unroll
    for (int nb = 0; nb < 2; ++nb) {
        const int node = wave * 2 + nb;
        const int n = n0 + node;
        const int rs = offs[n], re = offs[n + 1];
        float g1 = 0.f, vmx = -INFINITY, s2 = 0.f, s3 = 0.f, sw = 0.f;

        for (int base = rs; base < re; base += 64) {
            const int cnt = min(64, re - base);
            int sl = 0; int wli = 0;
            if (lane < cnt) {
                int2 ew = csr[base + lane];
                sl = ew.x; wli = ew.y;
            }
            const int cm1 = cnt - 1;
            for (int jj = 0; jj < cnt; jj += 8) {
                unsigned short fv[8]; unsigned int hv[8];
                #pragma unroll
                for (int u = 0; u < 8; ++u) {
                    int ic = min(jj + u, cm1);
                    int sj = __builtin_amdgcn_readlane(sl, ic);
                    fv[u] = featb[(size_t)sj * 64 + lane];
                    hv[u] = hmsp[(size_t)sj * 64 + lane];
                }
                #pragma unroll
                for (int u = 0; u < 8; ++u) {
                    int ic = min(jj + u, cm1);
                    bool valid = (jj + u) < cnt;
                    float wj = __int_as_float(__builtin_amdgcn_readlane(wli, ic));
                    wj = valid ? wj : 0.f;
                    float f  = bf2f(fv[u]);
                    float hm = bf2f_lo(hv[u]);
                    float hs = bf2f_hi(hv[u]);
                    g1 = fmaf(wj, f, g1);
                    float m = valid ? wj * hm : -INFINITY;
                    vmx = fmaxf(vmx, m);
                    s3 = fmaf(wj, hs, s3);
                    s2 = fmaf(wj * hs, hs, s2);
                    sw += wj;
                }
            }
        }

        const int dg = re - rs;
        const float inv = 1.0f / (float)max(dg, 1);
        const float m1 = s3 * inv;
        const float astd = (dg > 0) ? (s2 * inv - m1 * m1) : 0.f;
        unsigned short* row = x2 + node * X2S;
        row[lane]       = f2bf(g1);
        row[64 + lane]  = f2bf(g1 * inv);
        row[128 + lane] = f2bf(dg > 0 ? vmx : 0.f);
        row[192 + lane] = f2bf(astd);
        if (lane == 0) { swl[node] = sw; invl[node] = inv; }
    }
    __syncthreads();

    // ---- phase 2: epilogue on waves 0-3 ----
    if (wave >= 4) return;
    const int nr = lane & 15;
    const int kq = (lane >> 4) * 8;
    const int col = wave * 16 + nr;
    const int orow = (lane >> 4) * 4;

    f32x4 acc = (f32x4){0.f, 0.f, 0.f, 0.f};
    #pragma unroll
    for (int s = 0; s < 2; ++s) {
        short8v a = *(const short8v*)(featb + (size_t)(n0 + nr) * 64 + s * 32 + kq);
        short8v b = *(const short8v*)(wnb2 + (size_t)col * 320 + s * 32 + kq);
        acc = __builtin_amdgcn_mfma_f32_16x16x32_bf16(a, b, acc, 0, 0, 0);
    }
    #pragma unroll
    for (int s = 2; s < 10; ++s) {
        short8v a = *(const short8v*)(x2 + nr * X2S + (s - 2) * 32 + kq);
        short8v b = *(const short8v*)(wnb2 + (size_t)col * 320 + s * 32 + kq);
        acc = __builtin_amdgcn_mfma_f32_16x16x32_bf16(a, b, acc, 0, 0, 0);
    }

    const float bb = bn[col], uu = uvec[col], vv = vvec[col];
    #pragma unroll
    for (int i = 0; i < 4; ++i) {
        const int node = orow + i;
        const float o = acc[i] + bb + swl[node] * uu + swl[node] * invl[node] * vv;
        out[(size_t)(n0 + node) * 64 + col] = o;
    }
}

extern "C" void kernel_launch(void* const* d_in, const int* in_sizes, int n_in,
                              void* d_out, int out_size, void* d_ws, size_t ws_size,
                              hipStream_t stream)
{
    const float* feat   = (const float*)d_in[0];
    const float* weight = (const float*)d_in[1];
    const int*   src    = (const int*)d_in[2];
    const int*   dst    = (const int*)d_in[3];
    const float* Wp     = (const float*)d_in[4];
    const float* bp     = (const float*)d_in[5];
    const float* Wn     = (const float*)d_in[6];
    const float* bn     = (const float*)d_in[7];
    float* out = (float*)d_out;

    char* ws = (char*)d_ws;
    size_t cur = 0;
    auto alloc = [&](size_t bytes) -> void* {
        cur = (cur + 255) & ~(size_t)255;
        void* p = ws + cur;
        cur += bytes;
        return p;
    };

    unsigned short* hms  = (unsigned short*)alloc((size_t)NN * 128 * 2);
    int* degcur          = (int*)alloc((size_t)2 * NN * 4);   // deg | cursor
    int* deg    = degcur;
    int* cursor = degcur + NN;
    int* offs   = (int*)alloc((size_t)(NN + 1) * 4);
    int* bsum   = (int*)alloc(1024);
    int2* csr   = (int2*)alloc((size_t)NE * 8);
    unsigned short* featb= (unsigned short*)alloc((size_t)NN * 64 * 2);
    unsigned short* wnb2 = (unsigned short*)alloc((size_t)64 * 320 * 2);
    unsigned short* wpb2 = (unsigned short*)alloc((size_t)128 * 64 * 2);
    float* bpp2          = (float*)alloc((size_t)128 * 4);
    float* uvec          = (float*)alloc((size_t)64 * 4);
    float* vvec          = (float*)alloc((size_t)64 * 4);
    (void)ws_size; (void)in_sizes; (void)n_in; (void)out_size;

    cvt_w_kernel<<<129, 256, 0, stream>>>(Wp, bp, Wn, wnb2, wpb2, bpp2, uvec, vvec,
                                          (int4*)degcur);
    pool_mfma_kernel<<<(NTILE16 + 3) / 4, 256, 0, stream>>>(feat, dst, deg, wpb2, bpp2, featb, hms);
    scan1<<<NBLK, 256, 0, stream>>>(deg, bsum);
    scan3<<<NBLK, 256, 0, stream>>>(deg, bsum, offs);
    scatter_kernel<<<(NE + 255) / 256, 256, 0, stream>>>(src, dst, weight, offs, cursor, csr);
    fused_gather_epi_kernel<<<NTILE16, 512, 0, stream>>>(featb, hms, offs, csr, wnb2,
                                                         bn, uvec, vvec, out);
}